// Round 14
// baseline (781.593 us; speedup 1.0000x reference)
//
#include <hip/hip_runtime.h>
#include <hip/hip_bf16.h>
#include <cstdint>
#include <cstddef>

#define DD 64

typedef __attribute__((ext_vector_type(8))) short short8;
typedef __attribute__((ext_vector_type(4))) float f32x4;

__device__ __forceinline__ float4 f4_0() { return make_float4(0.f, 0.f, 0.f, 0.f); }

__device__ __forceinline__ unsigned short f2bf(float f) {
  __hip_bfloat16 h = __float2bfloat16(f);
  return *reinterpret_cast<unsigned short*>(&h);
}
__device__ __forceinline__ float bfl(unsigned u) { return __uint_as_float(u << 16); }
__device__ __forceinline__ float bfh(unsigned u) { return __uint_as_float(u & 0xffff0000u); }
__device__ __forceinline__ float b2f(unsigned short u) {
  return __uint_as_float(((unsigned)u) << 16);
}

__device__ __forceinline__ short8 pack_bf16x8(float4 a, float4 b) {
  union { unsigned short us[8]; short8 v; } pk;
  pk.us[0] = f2bf(a.x); pk.us[1] = f2bf(a.y); pk.us[2] = f2bf(a.z); pk.us[3] = f2bf(a.w);
  pk.us[4] = f2bf(b.x); pk.us[5] = f2bf(b.y); pk.us[6] = f2bf(b.z); pk.us[7] = f2bf(b.w);
  return pk.v;
}

__device__ __forceinline__ short8 lds_frag(const unsigned short* p) {
  uint2 lo = *reinterpret_cast<const uint2*>(p);
  uint2 hi = *reinterpret_cast<const uint2*>(p + 4);
  union { unsigned u[4]; short8 v; } t;
  t.u[0] = lo.x; t.u[1] = lo.y; t.u[2] = hi.x; t.u[3] = hi.y;
  return t.v;
}
__device__ __forceinline__ short8 g_frag(const unsigned short* p) {
  return *reinterpret_cast<const short8*>(p);
}

// XCD-aware bijective block swizzle (gridDim.x divisible by 8).
__device__ __forceinline__ int xcd_vb() {
  return (blockIdx.x & 7) * (gridDim.x >> 3) + (blockIdx.x >> 3);
}

// ---------- CSR build ----------
__global__ __launch_bounds__(256) void k_hist(const int* __restrict__ dst,
                                              int* __restrict__ cnt, int E) {
  int j = blockIdx.x * 256 + threadIdx.x;
  if (j < E) atomicAdd(&cnt[dst[j]], 1);
}

__global__ __launch_bounds__(1024) void k_scan(const int* __restrict__ cnt,
                                               int* __restrict__ row_ptr,
                                               int* __restrict__ nxt, int N, int E) {
  __shared__ int wsum[16];
  __shared__ int carry_s;
  const int tid = threadIdx.x;
  const int wid = tid >> 6, lane = tid & 63;
  if (tid == 0) carry_s = 0;
  __syncthreads();
  const int ntl = (N + 4095) / 4096;
  for (int b = 0; b < ntl; ++b) {
    const int i0 = b * 4096 + tid * 4;
    int v0 = 0, v1 = 0, v2 = 0, v3 = 0;
    if (i0 + 3 < N) {
      int4 q = *reinterpret_cast<const int4*>(cnt + i0);
      v0 = q.x; v1 = q.y; v2 = q.z; v3 = q.w;
    } else {
      if (i0 < N) v0 = cnt[i0];
      if (i0 + 1 < N) v1 = cnt[i0 + 1];
      if (i0 + 2 < N) v2 = cnt[i0 + 2];
      if (i0 + 3 < N) v3 = cnt[i0 + 3];
    }
    const int tsum = v0 + v1 + v2 + v3;
    int x = tsum;
#pragma unroll
    for (int off = 1; off < 64; off <<= 1) {
      int y = __shfl_up(x, off, 64);
      if (lane >= off) x += y;
    }
    if (lane == 63) wsum[wid] = x;
    __syncthreads();
    if (wid == 0 && lane < 16) {
      int wv = wsum[lane];
#pragma unroll
      for (int off = 1; off < 16; off <<= 1) {
        int y = __shfl_up(wv, off, 64);
        if (lane >= off) wv += y;
      }
      wsum[lane] = wv;
    }
    __syncthreads();
    int base = carry_s + (wid > 0 ? wsum[wid - 1] : 0) + (x - tsum);
    int e1 = base + v0, e2 = e1 + v1, e3 = e2 + v2;
    if (i0 < N) { row_ptr[i0] = base; nxt[i0] = base; }
    if (i0 + 1 < N) { row_ptr[i0 + 1] = e1; nxt[i0 + 1] = e1; }
    if (i0 + 2 < N) { row_ptr[i0 + 2] = e2; nxt[i0 + 2] = e2; }
    if (i0 + 3 < N) { row_ptr[i0 + 3] = e3; nxt[i0 + 3] = e3; }
    __syncthreads();
    if (tid == 0) carry_s += wsum[15];
    __syncthreads();
  }
  if (tid == 0) row_ptr[N] = E;
}

__global__ __launch_bounds__(256) void k_scatter(const int* __restrict__ dst,
                                                 const int* __restrict__ src,
                                                 int* __restrict__ nxt,
                                                 int* __restrict__ order,
                                                 int* __restrict__ psrc,
                                                 int2* __restrict__ pedge, int E) {
  int j = blockIdx.x * 256 + threadIdx.x;
  if (j >= E) return;
  int d = dst[j];
  int s = src[j];
  int pos = atomicAdd(&nxt[d], 1);
  order[pos] = j;
  psrc[pos] = s;
  pedge[pos] = make_int2(s, d);
}

// ---------- weight pre-transpose to bf16 ----------
__global__ __launch_bounds__(256) void k_prep(const float* __restrict__ A1,
                                              const float* __restrict__ A2,
                                              const float* __restrict__ V,
                                              const float* __restrict__ U,
                                              const float* __restrict__ A3,
                                              const float* __restrict__ W1,
                                              unsigned short* __restrict__ T) {
  const int b = blockIdx.x;
  const int tid = threadIdx.x;
  if (b < 20) {
    const int l = b / 5, m = b % 5;
    const float* srcp =
        (m == 0 ? A1 : m == 1 ? A2 : m == 2 ? V : m == 3 ? U : A3) + l * 4096;
    unsigned short* dstp = T + b * 4096;
    for (int i = tid; i < 4096; i += 256) {
      int n = i >> 6, k = i & 63;
      dstp[i] = f2bf(srcp[k * 64 + n]);
    }
  } else {
    unsigned short* dstp = T + 20 * 4096;
    for (int i = tid; i < 12288; i += 256) {
      int n = i / 192, k = i % 192;
      dstp[i] = f2bf(W1[k * 64 + n]);
    }
  }
}

// ---------- conv staging helpers ----------
struct ConvRegs { float4 v[3][2]; };

__device__ __forceinline__ void conv_load(const float* __restrict__ reads, int N,
                                          int g, int tid, ConvRegs& R) {
#pragma unroll
  for (int it = 0; it < 3; ++it) {
    const int task = tid + it * 256;
    R.v[it][0] = f4_0(); R.v[it][1] = f4_0();
    if (task < 576) {
      const int node = task / 144, rem = task % 144;
      const int c = rem / 36, u = rem % 36;
      const int gn = g * 4 + node;
      if (gn < N) {
        const float* rp = reads + (size_t)gn * 512 + c * 128 + 4 * u;
        if (u <= 31) R.v[it][0] = *reinterpret_cast<const float4*>(rp);
        if (u <= 30) R.v[it][1] = *reinterpret_cast<const float4*>(rp + 4);
      }
    }
  }
}

__device__ __forceinline__ void conv_write(unsigned short* __restrict__ cbuf,
                                           int tid, const ConvRegs& R) {
#pragma unroll
  for (int it = 0; it < 3; ++it) {
    const int task = tid + it * 256;
    if (task < 576) {
      const int node = task / 144, rem = task % 144;
      const int c = rem / 36, u = rem % 36;
      const float4 v0 = R.v[it][0], v1 = R.v[it][1];
      unsigned pk0, pk1, pk2, pk3;
      asm("v_cvt_pk_bf16_f32 %0, %1, %2" : "=v"(pk0) : "v"(v0.x), "v"(v0.y));
      asm("v_cvt_pk_bf16_f32 %0, %1, %2" : "=v"(pk1) : "v"(v0.z), "v"(v0.w));
      asm("v_cvt_pk_bf16_f32 %0, %1, %2" : "=v"(pk2) : "v"(v1.x), "v"(v1.y));
      asm("v_cvt_pk_bf16_f32 %0, %1, %2" : "=v"(pk3) : "v"(v1.z), "v"(v1.w));
      const unsigned a0 = __builtin_amdgcn_alignbit(pk1, pk0, 16);
      const unsigned a1 = __builtin_amdgcn_alignbit(pk2, pk1, 16);
      const unsigned a2 = __builtin_amdgcn_alignbit(pk3, pk2, 16);
      const int base = ((node * 4 + c) * 4) * 144 + 4 * u;
      *reinterpret_cast<uint2*>(&cbuf[base + 0 * 144]) = make_uint2(pk0, pk1);
      *reinterpret_cast<uint2*>(&cbuf[base + 1 * 144]) = make_uint2(a0, a1);
      *reinterpret_cast<uint2*>(&cbuf[base + 2 * 144]) = make_uint2(pk1, pk2);
      *reinterpret_cast<uint2*>(&cbuf[base + 3 * 144]) = make_uint2(a1, a2);
    }
  }
}

// ---------- conv1d + maxpool: persistent, double-buffered LDS staging ----------
__global__ __launch_bounds__(256) void k_conv_mfma(const float* __restrict__ reads,
                                                   const float* __restrict__ w,
                                                   const float* __restrict__ bias,
                                                   float* __restrict__ h, int N) {
  __shared__ unsigned short cp[2][4 * 4 * 4 * 144];  // double buffer, 36 KB
  const int tid = threadIdx.x;
  const int wid = tid >> 6, lane = tid & 63;
  const int col = lane & 15, grp = lane >> 4;
  const int ngroups = (N + 3) / 4;
  if ((int)blockIdx.x >= ngroups) return;
  short8 wf[4][2];
#pragma unroll
  for (int nt = 0; nt < 4; ++nt)
#pragma unroll
    for (int ks = 0; ks < 2; ++ks) {
      const int d = nt * 16 + col;
      const int kb = ks * 32 + grp * 8;
      const float* wp = w + d * 64 + kb;
      float4 w0 = *reinterpret_cast<const float4*>(wp);
      float4 w1 = *reinterpret_cast<const float4*>(wp + 4);
      wf[nt][ks] = pack_bf16x8(w0, w1);
    }
  ConvRegs RA, RB;
  conv_load(reads, N, blockIdx.x, tid, RA);
  int p = 0;
  const int s = col & 3;
  for (int g = blockIdx.x; g < ngroups; g += gridDim.x) {
    conv_write(&cp[p][0], tid, RA);
    const int gnext = g + gridDim.x;
    if (gnext < ngroups) conv_load(reads, N, gnext, tid, RB);
    __syncthreads();
    const int gn = g * 4 + wid;
    if (gn < N) {
      const unsigned short* cbuf = &cp[p][0];
      float vmax[4];
#pragma unroll
      for (int nt = 0; nt < 4; ++nt) vmax[nt] = -3.0e38f;
      for (int mt = 0; mt < 8; ++mt) {
        const int t = mt * 16 + col;
        short8 af[2];
#pragma unroll
        for (int ks = 0; ks < 2; ++ks) {
          const int kbase = ks * 32 + grp * 8;
          const int c = kbase >> 4;
          const int kk0 = kbase & 15;
          const int q = (t - s) + kk0;
          af[ks] = lds_frag(&cbuf[((wid * 4 + c) * 4 + s) * 144 + q]);
        }
        f32x4 acc[4] = {};
#pragma unroll
        for (int ks = 0; ks < 2; ++ks)
#pragma unroll
          for (int nt = 0; nt < 4; ++nt)
            acc[nt] = __builtin_amdgcn_mfma_f32_16x16x32_bf16(af[ks], wf[nt][ks], acc[nt], 0, 0, 0);
        if (mt < 7) {
#pragma unroll
          for (int nt = 0; nt < 4; ++nt)
#pragma unroll
            for (int r = 0; r < 4; ++r) vmax[nt] = fmaxf(vmax[nt], acc[nt][r]);
        } else {
          if (grp == 0) {
#pragma unroll
            for (int nt = 0; nt < 4; ++nt) vmax[nt] = fmaxf(vmax[nt], acc[nt][0]);
          }
        }
      }
#pragma unroll
      for (int off = 16; off <= 32; off <<= 1)
#pragma unroll
        for (int nt = 0; nt < 4; ++nt)
          vmax[nt] = fmaxf(vmax[nt], __shfl_xor(vmax[nt], off, 64));
      if (grp == 0) {
#pragma unroll
        for (int nt = 0; nt < 4; ++nt) {
          const int d = nt * 16 + col;
          h[(size_t)gn * 64 + d] = vmax[nt] + bias[d];
        }
      }
    }
    p ^= 1;
    RA = RB;
  }
}

// ---------- persistent node MFMA: fused h-update + 4 GEMMs ----------
__global__ __launch_bounds__(256) void k_node_mfma(const float* __restrict__ h_in,
                                                   float* __restrict__ h_out,
                                                   const float* __restrict__ hhat,
                                                   const float* __restrict__ sums_prev,
                                                   const float* __restrict__ gam,
                                                   const float* __restrict__ bet,
                                                   const unsigned short* __restrict__ Wt4,
                                                   const float* __restrict__ bA1,
                                                   const float* __restrict__ bA2,
                                                   const float* __restrict__ bV,
                                                   const float* __restrict__ bU,
                                                   unsigned short* __restrict__ XA1,
                                                   unsigned short* __restrict__ XA2,
                                                   unsigned short* __restrict__ XV,
                                                   float* __restrict__ XU,
                                                   int N, int hasupd) {
  __shared__ float s_coef[128];
  const int tid = threadIdx.x;
  if (hasupd) {
    if (tid < 64) {
      const float invR = 1.f / (float)N;
      float mean = sums_prev[tid] * invR;
      float var = sums_prev[64 + tid] * invR - mean * mean;
      float sc = gam[tid] * rsqrtf(var + 1e-5f);
      s_coef[tid] = sc;
      s_coef[64 + tid] = bet[tid] - mean * sc;
    }
    __syncthreads();
  }
  const int wid = tid >> 6, lane = tid & 63;
  const int col = lane & 15, g = lane >> 4;
  const int ntiles = (N + 15) / 16;
  for (int tw = blockIdx.x * 4 + wid; tw < ntiles; tw += gridDim.x * 4) {
    int n = tw * 16 + col;
    const bool valid = n < N;
    if (!valid) n = N - 1;
    short8 bfr[2];
#pragma unroll
    for (int ks = 0; ks < 2; ++ks) {
      const int c0 = ks * 32 + g * 8;
      const float* hp = h_in + (size_t)n * 64 + c0;
      float4 x0 = *reinterpret_cast<const float4*>(hp);
      float4 x1 = *reinterpret_cast<const float4*>(hp + 4);
      if (hasupd) {
        const float* yp = hhat + (size_t)n * 64 + c0;
        float4 y0 = *reinterpret_cast<const float4*>(yp);
        float4 y1 = *reinterpret_cast<const float4*>(yp + 4);
        float4 sc0 = *reinterpret_cast<const float4*>(&s_coef[c0]);
        float4 sc1 = *reinterpret_cast<const float4*>(&s_coef[c0 + 4]);
        float4 sh0 = *reinterpret_cast<const float4*>(&s_coef[64 + c0]);
        float4 sh1 = *reinterpret_cast<const float4*>(&s_coef[64 + c0 + 4]);
        x0.x += fmaxf(fmaf(sc0.x, y0.x, sh0.x), 0.f);
        x0.y += fmaxf(fmaf(sc0.y, y0.y, sh0.y), 0.f);
        x0.z += fmaxf(fmaf(sc0.z, y0.z, sh0.z), 0.f);
        x0.w += fmaxf(fmaf(sc0.w, y0.w, sh0.w), 0.f);
        x1.x += fmaxf(fmaf(sc1.x, y1.x, sh1.x), 0.f);
        x1.y += fmaxf(fmaf(sc1.y, y1.y, sh1.y), 0.f);
        x1.z += fmaxf(fmaf(sc1.z, y1.z, sh1.z), 0.f);
        x1.w += fmaxf(fmaf(sc1.w, y1.w, sh1.w), 0.f);
        if (valid) {
          float* op = h_out + (size_t)n * 64 + c0;
          *reinterpret_cast<float4*>(op) = x0;
          *reinterpret_cast<float4*>(op + 4) = x1;
        }
      }
      bfr[ks] = pack_bf16x8(x0, x1);
    }
#pragma unroll
    for (int m = 0; m < 4; ++m) {
      const unsigned short* Wm = Wt4 + m * 4096;
      f32x4 acc[4] = {};
#pragma unroll
      for (int ks = 0; ks < 2; ++ks) {
        const int ko = ks * 32 + g * 8;
#pragma unroll
        for (int mt = 0; mt < 4; ++mt) {
          short8 aa = g_frag(Wm + (mt * 16 + col) * 64 + ko);
          acc[mt] = __builtin_amdgcn_mfma_f32_16x16x32_bf16(aa, bfr[ks], acc[mt], 0, 0, 0);
        }
      }
      if (!valid) continue;
      const float* bb = (m == 0) ? bA1 : (m == 1) ? bA2 : (m == 2) ? bV : bU;
#pragma unroll
      for (int mt = 0; mt < 4; ++mt) {
        const int chb = mt * 16 + g * 4;
        float4 bv = *reinterpret_cast<const float4*>(bb + chb);
        float o0 = acc[mt][0] + bv.x;
        float o1 = acc[mt][1] + bv.y;
        float o2 = acc[mt][2] + bv.z;
        float o3 = acc[mt][3] + bv.w;
        if (m < 3) {
          unsigned short* X = (m == 0) ? XA1 : (m == 1) ? XA2 : XV;
          ushort4 ov;
          ov.x = f2bf(o0); ov.y = f2bf(o1); ov.z = f2bf(o2); ov.w = f2bf(o3);
          *reinterpret_cast<ushort4*>(X + (size_t)n * 64 + chb) = ov;
        } else {
          *reinterpret_cast<float4*>(XU + (size_t)n * 64 + chb) =
              make_float4(o0, o1, o2, o3);
        }
      }
    }
  }
}

// ---------- layer-0 edge MFMA: fused edge-encoder + BN stats; prefetched; XCD swizzle ----------
__global__ __launch_bounds__(256) void k_edge_mfma0(unsigned short* __restrict__ e,
                                                    unsigned short* __restrict__ ehat_out,
                                                    const float* __restrict__ sim,
                                                    const float* __restrict__ olen,
                                                    const int* __restrict__ order,
                                                    const float* __restrict__ We,
                                                    const float* __restrict__ be,
                                                    const int2* __restrict__ pedge,
                                                    const unsigned short* __restrict__ XA1,
                                                    const unsigned short* __restrict__ XA2,
                                                    const unsigned short* __restrict__ A3t,
                                                    const float* __restrict__ bA3,
                                                    float* __restrict__ sums_out, int E) {
  __shared__ float s_sums[128];
  const int tid = threadIdx.x;
  if (tid < 128) s_sums[tid] = 0.f;
  __syncthreads();
  const int wid = tid >> 6, lane = tid & 63;
  const int col = lane & 15, g = lane >> 4;
  float4 ba[4];
#pragma unroll
  for (int mt = 0; mt < 4; ++mt)
    ba[mt] = *reinterpret_cast<const float4*>(bA3 + mt * 16 + g * 4);
  float4 w0[2][2], w1[2][2], bev[2][2];
#pragma unroll
  for (int ks = 0; ks < 2; ++ks) {
    const int c0 = ks * 32 + g * 8;
    w0[ks][0] = *reinterpret_cast<const float4*>(We + c0);
    w0[ks][1] = *reinterpret_cast<const float4*>(We + c0 + 4);
    w1[ks][0] = *reinterpret_cast<const float4*>(We + 64 + c0);
    w1[ks][1] = *reinterpret_cast<const float4*>(We + 64 + c0 + 4);
    bev[ks][0] = *reinterpret_cast<const float4*>(be + c0);
    bev[ks][1] = *reinterpret_cast<const float4*>(be + c0 + 4);
  }
  float statS[16], statQ[16];
#pragma unroll
  for (int i = 0; i < 16; ++i) { statS[i] = 0.f; statQ[i] = 0.f; }
  const int ntiles = (E + 15) / 16;
  const int stride = gridDim.x * 4;
  int tw = xcd_vb() * 4 + wid;
  int2 idx_n = make_int2(0, 0);
  int oe_n = 0;
  if (tw < ntiles) {
    int p = tw * 16 + col; if (p >= E) p = E - 1;
    idx_n = pedge[p];
    oe_n = order[p];
  }
  for (; tw < ntiles; tw += stride) {
    int p = tw * 16 + col;
    const bool valid = p < E;
    if (!valid) p = E - 1;
    const int se = idx_n.x, de = idx_n.y;
    const float sv = sim[oe_n], lv = olen[oe_n];
    ushort4 gx1[4], gx2[4];
#pragma unroll
    for (int mt = 0; mt < 4; ++mt) {
      const int chb = mt * 16 + g * 4;
      gx1[mt] = *reinterpret_cast<const ushort4*>(XA1 + (size_t)se * 64 + chb);
      gx2[mt] = *reinterpret_cast<const ushort4*>(XA2 + (size_t)de * 64 + chb);
    }
    const int twn = tw + stride;
    if (twn < ntiles) {
      int pn = twn * 16 + col; if (pn >= E) pn = E - 1;
      idx_n = pedge[pn];
      oe_n = order[pn];
    }
    short8 bfr[2];
#pragma unroll
    for (int ks = 0; ks < 2; ++ks) {
      float4 e0, e1;
      e0.x = fmaf(sv, w0[ks][0].x, fmaf(lv, w1[ks][0].x, bev[ks][0].x));
      e0.y = fmaf(sv, w0[ks][0].y, fmaf(lv, w1[ks][0].y, bev[ks][0].y));
      e0.z = fmaf(sv, w0[ks][0].z, fmaf(lv, w1[ks][0].z, bev[ks][0].z));
      e0.w = fmaf(sv, w0[ks][0].w, fmaf(lv, w1[ks][0].w, bev[ks][0].w));
      e1.x = fmaf(sv, w0[ks][1].x, fmaf(lv, w1[ks][1].x, bev[ks][1].x));
      e1.y = fmaf(sv, w0[ks][1].y, fmaf(lv, w1[ks][1].y, bev[ks][1].y));
      e1.z = fmaf(sv, w0[ks][1].z, fmaf(lv, w1[ks][1].z, bev[ks][1].z));
      e1.w = fmaf(sv, w0[ks][1].w, fmaf(lv, w1[ks][1].w, bev[ks][1].w));
      bfr[ks] = pack_bf16x8(e0, e1);
      if (valid)
        *reinterpret_cast<short8*>(e + (size_t)p * 64 + ks * 32 + g * 8) = bfr[ks];
    }
    f32x4 acc[4] = {};
#pragma unroll
    for (int ks = 0; ks < 2; ++ks)
#pragma unroll
      for (int mt = 0; mt < 4; ++mt) {
        short8 aa = g_frag(A3t + (mt * 16 + col) * 64 + ks * 32 + g * 8);
        acc[mt] = __builtin_amdgcn_mfma_f32_16x16x32_bf16(aa, bfr[ks], acc[mt], 0, 0, 0);
      }
    if (valid) {
#pragma unroll
      for (int mt = 0; mt < 4; ++mt) {
        const int chb = mt * 16 + g * 4;
        float o0 = acc[mt][0] + b2f(gx1[mt].x) + b2f(gx2[mt].x) + ba[mt].x;
        float o1 = acc[mt][1] + b2f(gx1[mt].y) + b2f(gx2[mt].y) + ba[mt].y;
        float o2 = acc[mt][2] + b2f(gx1[mt].z) + b2f(gx2[mt].z) + ba[mt].z;
        float o3 = acc[mt][3] + b2f(gx1[mt].w) + b2f(gx2[mt].w) + ba[mt].w;
        ushort4 ov;
        ov.x = f2bf(o0); ov.y = f2bf(o1); ov.z = f2bf(o2); ov.w = f2bf(o3);
        *reinterpret_cast<ushort4*>(ehat_out + (size_t)p * 64 + chb) = ov;
        statS[mt * 4 + 0] += o0; statQ[mt * 4 + 0] = fmaf(o0, o0, statQ[mt * 4 + 0]);
        statS[mt * 4 + 1] += o1; statQ[mt * 4 + 1] = fmaf(o1, o1, statQ[mt * 4 + 1]);
        statS[mt * 4 + 2] += o2; statQ[mt * 4 + 2] = fmaf(o2, o2, statQ[mt * 4 + 2]);
        statS[mt * 4 + 3] += o3; statQ[mt * 4 + 3] = fmaf(o3, o3, statQ[mt * 4 + 3]);
      }
    }
  }
#pragma unroll
  for (int off = 1; off <= 8; off <<= 1)
#pragma unroll
    for (int i = 0; i < 16; ++i) {
      statS[i] += __shfl_xor(statS[i], off, 64);
      statQ[i] += __shfl_xor(statQ[i], off, 64);
    }
  if (col == 0) {
#pragma unroll
    for (int mt = 0; mt < 4; ++mt)
#pragma unroll
      for (int c = 0; c < 4; ++c) {
        const int ch = mt * 16 + g * 4 + c;
        atomicAdd(&s_sums[ch], statS[mt * 4 + c]);
        atomicAdd(&s_sums[64 + ch], statQ[mt * 4 + c]);
      }
  }
  __syncthreads();
  if (tid < 128) atomicAdd(&sums_out[tid], s_sums[tid]);
}

// ---------- layers 1..3 edge MFMA: 2-DEEP prefetched streams, fused e-update + BN stats ----------
__global__ __launch_bounds__(256) void k_edge_mfma(unsigned short* __restrict__ e,
                                                   const unsigned short* __restrict__ ehat_prev,
                                                   unsigned short* __restrict__ ehat_out,
                                                   const float* __restrict__ sums_prev,
                                                   const float* __restrict__ gprev,
                                                   const float* __restrict__ bprev,
                                                   const int2* __restrict__ pedge,
                                                   const unsigned short* __restrict__ XA1,
                                                   const unsigned short* __restrict__ XA2,
                                                   const unsigned short* __restrict__ A3t,
                                                   const float* __restrict__ bA3,
                                                   float* __restrict__ sums_out, int E) {
  __shared__ float s_coef[128];
  __shared__ float s_sums[128];
  const int tid = threadIdx.x;
  if (tid < 128) s_sums[tid] = 0.f;
  if (tid < 64) {
    float mean = sums_prev[tid] / (float)E;
    float var = sums_prev[64 + tid] / (float)E - mean * mean;
    float sc = gprev[tid] * rsqrtf(var + 1e-5f);
    s_coef[tid] = sc;
    s_coef[64 + tid] = bprev[tid] - mean * sc;
  }
  __syncthreads();
  const int wid = tid >> 6, lane = tid & 63;
  const int col = lane & 15, g = lane >> 4;
  float4 ba[4];
#pragma unroll
  for (int mt = 0; mt < 4; ++mt)
    ba[mt] = *reinterpret_cast<const float4*>(bA3 + mt * 16 + g * 4);
  float statS[16], statQ[16];
#pragma unroll
  for (int i = 0; i < 16; ++i) { statS[i] = 0.f; statQ[i] = 0.f; }
  const int ntiles = (E + 15) / 16;
  const int stride = gridDim.x * 4;
  int tw = xcd_vb() * 4 + wid;
  // 2-deep rotating prefetch: A = tile tw (arrived), B = tile tw+stride (in flight)
  int2 idxA = make_int2(0, 0), idxB = make_int2(0, 0);
  uint4 eoA0 = {}, eoA1 = {}, hvA0 = {}, hvA1 = {};
  uint4 eoB0 = {}, eoB1 = {}, hvB0 = {}, hvB1 = {};
  if (tw < ntiles) {
    int p = tw * 16 + col; if (p >= E) p = E - 1;
    idxA = pedge[p];
    const unsigned short* ep = e + (size_t)p * 64 + g * 8;
    eoA0 = *reinterpret_cast<const uint4*>(ep);
    eoA1 = *reinterpret_cast<const uint4*>(ep + 32);
    const unsigned short* hp = ehat_prev + (size_t)p * 64 + g * 8;
    hvA0 = *reinterpret_cast<const uint4*>(hp);
    hvA1 = *reinterpret_cast<const uint4*>(hp + 32);
  }
  if (tw + stride < ntiles) {
    int p = (tw + stride) * 16 + col; if (p >= E) p = E - 1;
    idxB = pedge[p];
    const unsigned short* ep = e + (size_t)p * 64 + g * 8;
    eoB0 = *reinterpret_cast<const uint4*>(ep);
    eoB1 = *reinterpret_cast<const uint4*>(ep + 32);
    const unsigned short* hp = ehat_prev + (size_t)p * 64 + g * 8;
    hvB0 = *reinterpret_cast<const uint4*>(hp);
    hvB1 = *reinterpret_cast<const uint4*>(hp + 32);
  }
  for (; tw < ntiles; tw += stride) {
    int p = tw * 16 + col;
    const bool valid = p < E;
    if (!valid) p = E - 1;
    const int se = idxA.x, de = idxA.y;
    // gathers for current tile (idx resident)
    ushort4 gx1[4], gx2[4];
#pragma unroll
    for (int mt = 0; mt < 4; ++mt) {
      const int chb = mt * 16 + g * 4;
      gx1[mt] = *reinterpret_cast<const ushort4*>(XA1 + (size_t)se * 64 + chb);
      gx2[mt] = *reinterpret_cast<const ushort4*>(XA2 + (size_t)de * 64 + chb);
    }
    // VALU: e-update consuming A's streams
    short8 bfr[2];
    {
      const uint4 eoc[2] = {eoA0, eoA1};
      const uint4 hvc[2] = {hvA0, hvA1};
#pragma unroll
      for (int ks = 0; ks < 2; ++ks) {
        const int c0 = ks * 32 + g * 8;
        const uint4 eo = eoc[ks];
        const uint4 hv = hvc[ks];
        float4 e0 = make_float4(bfl(eo.x), bfh(eo.x), bfl(eo.y), bfh(eo.y));
        float4 e1 = make_float4(bfl(eo.z), bfh(eo.z), bfl(eo.w), bfh(eo.w));
        float4 sc0 = *reinterpret_cast<const float4*>(&s_coef[c0]);
        float4 sc1 = *reinterpret_cast<const float4*>(&s_coef[c0 + 4]);
        float4 sh0 = *reinterpret_cast<const float4*>(&s_coef[64 + c0]);
        float4 sh1 = *reinterpret_cast<const float4*>(&s_coef[64 + c0 + 4]);
        e0.x += fmaxf(fmaf(sc0.x, bfl(hv.x), sh0.x), 0.f);
        e0.y += fmaxf(fmaf(sc0.y, bfh(hv.x), sh0.y), 0.f);
        e0.z += fmaxf(fmaf(sc0.z, bfl(hv.y), sh0.z), 0.f);
        e0.w += fmaxf(fmaf(sc0.w, bfh(hv.y), sh0.w), 0.f);
        e1.x += fmaxf(fmaf(sc1.x, bfl(hv.z), sh1.x), 0.f);
        e1.y += fmaxf(fmaf(sc1.y, bfh(hv.z), sh1.y), 0.f);
        e1.z += fmaxf(fmaf(sc1.z, bfl(hv.w), sh1.z), 0.f);
        e1.w += fmaxf(fmaf(sc1.w, bfh(hv.w), sh1.w), 0.f);
        bfr[ks] = pack_bf16x8(e0, e1);
        if (valid)
          *reinterpret_cast<short8*>(e + (size_t)p * 64 + c0) = bfr[ks];
      }
    }
    // rotate B -> A, then issue loads for tw + 2*stride into B
    idxA = idxB;
    eoA0 = eoB0; eoA1 = eoB1; hvA0 = hvB0; hvA1 = hvB1;
    const int twn2 = tw + 2 * stride;
    if (twn2 < ntiles) {
      int pn = twn2 * 16 + col; if (pn >= E) pn = E - 1;
      idxB = pedge[pn];
      const unsigned short* ep = e + (size_t)pn * 64 + g * 8;
      eoB0 = *reinterpret_cast<const uint4*>(ep);
      eoB1 = *reinterpret_cast<const uint4*>(ep + 32);
      const unsigned short* hp = ehat_prev + (size_t)pn * 64 + g * 8;
      hvB0 = *reinterpret_cast<const uint4*>(hp);
      hvB1 = *reinterpret_cast<const uint4*>(hp + 32);
    }
    // MFMA + epilogue
    f32x4 acc[4] = {};
#pragma unroll
    for (int ks = 0; ks < 2; ++ks)
#pragma unroll
      for (int mt = 0; mt < 4; ++mt) {
        short8 aa = g_frag(A3t + (mt * 16 + col) * 64 + ks * 32 + g * 8);
        acc[mt] = __builtin_amdgcn_mfma_f32_16x16x32_bf16(aa, bfr[ks], acc[mt], 0, 0, 0);
      }
    if (valid) {
#pragma unroll
      for (int mt = 0; mt < 4; ++mt) {
        const int chb = mt * 16 + g * 4;
        float o0 = acc[mt][0] + b2f(gx1[mt].x) + b2f(gx2[mt].x) + ba[mt].x;
        float o1 = acc[mt][1] + b2f(gx1[mt].y) + b2f(gx2[mt].y) + ba[mt].y;
        float o2 = acc[mt][2] + b2f(gx1[mt].z) + b2f(gx2[mt].z) + ba[mt].z;
        float o3 = acc[mt][3] + b2f(gx1[mt].w) + b2f(gx2[mt].w) + ba[mt].w;
        ushort4 ov;
        ov.x = f2bf(o0); ov.y = f2bf(o1); ov.z = f2bf(o2); ov.w = f2bf(o3);
        *reinterpret_cast<ushort4*>(ehat_out + (size_t)p * 64 + chb) = ov;
        statS[mt * 4 + 0] += o0; statQ[mt * 4 + 0] = fmaf(o0, o0, statQ[mt * 4 + 0]);
        statS[mt * 4 + 1] += o1; statQ[mt * 4 + 1] = fmaf(o1, o1, statQ[mt * 4 + 1]);
        statS[mt * 4 + 2] += o2; statQ[mt * 4 + 2] = fmaf(o2, o2, statQ[mt * 4 + 2]);
        statS[mt * 4 + 3] += o3; statQ[mt * 4 + 3] = fmaf(o3, o3, statQ[mt * 4 + 3]);
      }
    }
  }
#pragma unroll
  for (int off = 1; off <= 8; off <<= 1)
#pragma unroll
    for (int i = 0; i < 16; ++i) {
      statS[i] += __shfl_xor(statS[i], off, 64);
      statQ[i] += __shfl_xor(statQ[i], off, 64);
    }
  if (col == 0) {
#pragma unroll
    for (int mt = 0; mt < 4; ++mt)
#pragma unroll
      for (int c = 0; c < 4; ++c) {
        const int ch = mt * 16 + g * 4 + c;
        atomicAdd(&s_sums[ch], statS[mt * 4 + c]);
        atomicAdd(&s_sums[64 + ch], statQ[mt * 4 + c]);
      }
  }
  __syncthreads();
  if (tid < 128) atomicAdd(&sums_out[tid], s_sums[tid]);
}

// ---------- aggregation + hhat + fused h-stats (XCD swizzle) ----------
__global__ __launch_bounds__(256) void k_agg(const int* __restrict__ row_ptr,
                                             const int* __restrict__ psrc,
                                             const unsigned short* __restrict__ ehat,
                                             const unsigned short* __restrict__ XV,
                                             const float* __restrict__ XU,
                                             float* __restrict__ hhat,
                                             float* __restrict__ sums_h, int N) {
  __shared__ float s_sums[128];
  const int tid = threadIdx.x;
  if (tid < 128) s_sums[tid] = 0.f;
  __syncthreads();
  float sS[4] = {0.f, 0.f, 0.f, 0.f}, sQ[4] = {0.f, 0.f, 0.f, 0.f};
  const int total = N * 16;
  for (int idx = xcd_vb() * 256 + tid; idx < total; idx += gridDim.x * 256) {
    int n = idx >> 4, dc = (idx & 15) << 2;
    int beg = row_ptr[n], end = row_ptr[n + 1];
    float4 nm = f4_0(), dn = f4_0();
    for (int i = beg; i < end; ++i) {
      int sj = psrc[i];
      uint2 ev = *reinterpret_cast<const uint2*>(ehat + (size_t)i * 64 + dc);
      uint2 vv = *reinterpret_cast<const uint2*>(XV + (size_t)sj * 64 + dc);
      float s0 = 1.f / (1.f + __expf(-bfl(ev.x)));
      float s1 = 1.f / (1.f + __expf(-bfh(ev.x)));
      float s2 = 1.f / (1.f + __expf(-bfl(ev.y)));
      float s3 = 1.f / (1.f + __expf(-bfh(ev.y)));
      dn.x += s0; dn.y += s1; dn.z += s2; dn.w += s3;
      nm.x = fmaf(s0, bfl(vv.x), nm.x);
      nm.y = fmaf(s1, bfh(vv.x), nm.y);
      nm.z = fmaf(s2, bfl(vv.y), nm.z);
      nm.w = fmaf(s3, bfh(vv.y), nm.w);
    }
    float4 xu = *reinterpret_cast<const float4*>(XU + (size_t)n * 64 + dc);
    float h0 = xu.x + nm.x / (dn.x + 1e-6f);
    float h1 = xu.y + nm.y / (dn.y + 1e-6f);
    float h2 = xu.z + nm.z / (dn.z + 1e-6f);
    float h3 = xu.w + nm.w / (dn.w + 1e-6f);
    *reinterpret_cast<float4*>(hhat + (size_t)n * 64 + dc) = make_float4(h0, h1, h2, h3);
    sS[0] += h0; sQ[0] = fmaf(h0, h0, sQ[0]);
    sS[1] += h1; sQ[1] = fmaf(h1, h1, sQ[1]);
    sS[2] += h2; sQ[2] = fmaf(h2, h2, sQ[2]);
    sS[3] += h3; sQ[3] = fmaf(h3, h3, sQ[3]);
  }
#pragma unroll
  for (int off = 16; off <= 32; off <<= 1)
#pragma unroll
    for (int c = 0; c < 4; ++c) {
      sS[c] += __shfl_xor(sS[c], off, 64);
      sQ[c] += __shfl_xor(sQ[c], off, 64);
    }
  const int lane = tid & 63;
  if (lane < 16) {
    const int dc = lane << 2;
#pragma unroll
    for (int c = 0; c < 4; ++c) {
      atomicAdd(&s_sums[dc + c], sS[c]);
      atomicAdd(&s_sums[64 + dc + c], sQ[c]);
    }
  }
  __syncthreads();
  if (tid < 128) atomicAdd(&sums_h[tid], s_sums[tid]);
}

// ---------- final h-update: h += relu(BN(hhat)); also writes bf16 copy ----------
__global__ __launch_bounds__(256) void k_update_h(float* __restrict__ h,
                                                  unsigned short* __restrict__ hb,
                                                  const float* __restrict__ hhat,
                                                  const float* __restrict__ sums,
                                                  const float* __restrict__ gamma,
                                                  const float* __restrict__ beta, int R) {
  int idx = blockIdx.x * 256 + threadIdx.x;
  if (idx >= R * 16) return;
  int r = idx >> 4, dc = (idx & 15) << 2;
  const float invR = 1.f / (float)R;
  float4 sv = *reinterpret_cast<const float4*>(sums + dc);
  float4 qv = *reinterpret_cast<const float4*>(sums + 64 + dc);
  float4 gm = *reinterpret_cast<const float4*>(gamma + dc);
  float4 bt = *reinterpret_cast<const float4*>(beta + dc);
  float m0 = sv.x * invR, m1 = sv.y * invR, m2 = sv.z * invR, m3 = sv.w * invR;
  float c0 = gm.x * rsqrtf(qv.x * invR - m0 * m0 + 1e-5f);
  float c1 = gm.y * rsqrtf(qv.y * invR - m1 * m1 + 1e-5f);
  float c2 = gm.z * rsqrtf(qv.z * invR - m2 * m2 + 1e-5f);
  float c3 = gm.w * rsqrtf(qv.w * invR - m3 * m3 + 1e-5f);
  float h0 = bt.x - m0 * c0, h1 = bt.y - m1 * c1, h2 = bt.z - m2 * c2, h3 = bt.w - m3 * c3;
  size_t off = (size_t)r * 64 + dc;
  float4 y = *reinterpret_cast<const float4*>(hhat + off);
  float4 x = *reinterpret_cast<const float4*>(h + off);
  x.x += fmaxf(fmaf(c0, y.x, h0), 0.f);
  x.y += fmaxf(fmaf(c1, y.y, h1), 0.f);
  x.z += fmaxf(fmaf(c2, y.z, h2), 0.f);
  x.w += fmaxf(fmaf(c3, y.w, h3), 0.f);
  *reinterpret_cast<float4*>(h + off) = x;
  ushort4 hv;
  hv.x = f2bf(x.x); hv.y = f2bf(x.y); hv.z = f2bf(x.z); hv.w = f2bf(x.w);
  *reinterpret_cast<ushort4*>(hb + off) = hv;
}

// ---------- persistent decoder MFMA; bf16 h gathers, prefetched streams, XCD swizzle ----------
__global__ __launch_bounds__(256) void k_decoder_mfma(const unsigned short* __restrict__ hb,
                                                      const unsigned short* __restrict__ e,
                                                      const unsigned short* __restrict__ ehat3,
                                                      const float* __restrict__ sums_e3,
                                                      const float* __restrict__ ge3,
                                                      const float* __restrict__ be3,
                                                      const int2* __restrict__ pedge,
                                                      const int* __restrict__ order,
                                                      const unsigned short* __restrict__ W1t,
                                                      const float* __restrict__ b1,
                                                      const float* __restrict__ W2,
                                                      const float* __restrict__ b2,
                                                      float* __restrict__ out, int E) {
  __shared__ unsigned short Wt[64 * 200];
  __shared__ float s_coef[128];
  const int tid = threadIdx.x;
  if (tid < 64) {
    float mean = sums_e3[tid] / (float)E;
    float var = sums_e3[64 + tid] / (float)E - mean * mean;
    float sc = ge3[tid] * rsqrtf(var + 1e-5f);
    s_coef[tid] = sc;
    s_coef[64 + tid] = be3[tid] - mean * sc;
  }
  for (int i = tid; i < 1536; i += 256) {
    int n = i / 24, kc = (i % 24) * 8;
    *reinterpret_cast<uint4*>(&Wt[n * 200 + kc]) =
        *reinterpret_cast<const uint4*>(W1t + n * 192 + kc);
  }
  __syncthreads();
  const int wid = tid >> 6, lane = tid & 63;
  const int col = lane & 15, g = lane >> 4;
  float b1v[4], w2v[4];
#pragma unroll
  for (int nt = 0; nt < 4; ++nt) { b1v[nt] = b1[nt * 16 + col]; w2v[nt] = W2[nt * 16 + col]; }
  const float bb2 = b2[0];
  const int ntiles = (E + 15) / 16;
  const int stride = gridDim.x * 4;
  int tw = xcd_vb() * 4 + wid;
  int2 idx_n = make_int2(0, 0);
  uint4 eo_n0 = {}, eo_n1 = {}, hv_n0 = {}, hv_n1 = {};
  if (tw < ntiles) {
    int p = tw * 16 + col; if (p >= E) p = E - 1;
    idx_n = pedge[p];
    const unsigned short* ep = e + (size_t)p * 64 + g * 8;
    eo_n0 = *reinterpret_cast<const uint4*>(ep);
    eo_n1 = *reinterpret_cast<const uint4*>(ep + 32);
    const unsigned short* hp = ehat3 + (size_t)p * 64 + g * 8;
    hv_n0 = *reinterpret_cast<const uint4*>(hp);
    hv_n1 = *reinterpret_cast<const uint4*>(hp + 32);
  }
  for (; tw < ntiles; tw += stride) {
    const int eb = tw * 16;
    int p = eb + col;
    const bool valid = p < E;
    if (!valid) p = E - 1;
    const int se = idx_n.x, de = idx_n.y;
    const uint4 eoc[2] = {eo_n0, eo_n1};
    const uint4 hvc[2] = {hv_n0, hv_n1};
    short8 haf[4];
#pragma unroll
    for (int ks = 0; ks < 4; ++ks) {
      const unsigned short* hp = hb + (size_t)(ks < 2 ? se : de) * 64 + (ks & 1) * 32 + g * 8;
      haf[ks] = g_frag(hp);
    }
    const int twn = tw + stride;
    if (twn < ntiles) {
      int pn = twn * 16 + col; if (pn >= E) pn = E - 1;
      idx_n = pedge[pn];
      const unsigned short* ep = e + (size_t)pn * 64 + g * 8;
      eo_n0 = *reinterpret_cast<const uint4*>(ep);
      eo_n1 = *reinterpret_cast<const uint4*>(ep + 32);
      const unsigned short* hp = ehat3 + (size_t)pn * 64 + g * 8;
      hv_n0 = *reinterpret_cast<const uint4*>(hp);
      hv_n1 = *reinterpret_cast<const uint4*>(hp + 32);
    }
    f32x4 acc[4] = {};
#pragma unroll
    for (int ks = 0; ks < 6; ++ks) {
      short8 af;
      if (ks < 4) {
        af = haf[ks];
      } else {
        const int kse = ks - 4;
        const int c0 = kse * 32 + g * 8;
        const uint4 eo = eoc[kse];
        const uint4 hv = hvc[kse];
        float4 a0 = make_float4(bfl(eo.x), bfh(eo.x), bfl(eo.y), bfh(eo.y));
        float4 a1 = make_float4(bfl(eo.z), bfh(eo.z), bfl(eo.w), bfh(eo.w));
        float4 sc0 = *reinterpret_cast<const float4*>(&s_coef[c0]);
        float4 sc1 = *reinterpret_cast<const float4*>(&s_coef[c0 + 4]);
        float4 sh0 = *reinterpret_cast<const float4*>(&s_coef[64 + c0]);
        float4 sh1 = *reinterpret_cast<const float4*>(&s_coef[64 + c0 + 4]);
        a0.x += fmaxf(fmaf(sc0.x, bfl(hv.x), sh0.x), 0.f);
        a0.y += fmaxf(fmaf(sc0.y, bfh(hv.x), sh0.y), 0.f);
        a0.z += fmaxf(fmaf(sc0.z, bfl(hv.y), sh0.z), 0.f);
        a0.w += fmaxf(fmaf(sc0.w, bfh(hv.y), sh0.w), 0.f);
        a1.x += fmaxf(fmaf(sc1.x, bfl(hv.z), sh1.x), 0.f);
        a1.y += fmaxf(fmaf(sc1.y, bfh(hv.z), sh1.y), 0.f);
        a1.z += fmaxf(fmaf(sc1.z, bfl(hv.w), sh1.z), 0.f);
        a1.w += fmaxf(fmaf(sc1.w, bfh(hv.w), sh1.w), 0.f);
        af = pack_bf16x8(a0, a1);
      }
#pragma unroll
      for (int nt = 0; nt < 4; ++nt) {
        short8 bb = lds_frag(&Wt[(nt * 16 + col) * 200 + ks * 32 + g * 8]);
        acc[nt] = __builtin_amdgcn_mfma_f32_16x16x32_bf16(af, bb, acc[nt], 0, 0, 0);
      }
    }
    float pr[4];
#pragma unroll
    for (int r = 0; r < 4; ++r) {
      float s = 0.f;
#pragma unroll
      for (int nt = 0; nt < 4; ++nt)
        s = fmaf(fmaxf(acc[nt][r] + b1v[nt], 0.f), w2v[nt], s);
      pr[r] = s;
    }
#pragma unroll
    for (int off = 1; off <= 8; off <<= 1)
#pragma unroll
      for (int r = 0; r < 4; ++r)
        pr[r] += __shfl_xor(pr[r], off, 64);
    if (col == 0) {
#pragma unroll
      for (int r = 0; r < 4; ++r) {
        int m = eb + g * 4 + r;
        if (m < E) out[order[m]] = pr[r] + bb2;
      }
    }
  }
}

extern "C" void kernel_launch(void* const* d_in, const int* in_sizes, int n_in,
                              void* d_out, int out_size, void* d_ws, size_t ws_size,
                              hipStream_t stream) {
  const float* reads  = (const float*)d_in[0];
  const int*   src    = (const int*)d_in[1];
  const int*   dst    = (const int*)d_in[2];
  const float* sim    = (const float*)d_in[3];
  const float* olen   = (const float*)d_in[4];
  const float* conv_w = (const float*)d_in[5];
  const float* conv_b = (const float*)d_in[6];
  const float* We     = (const float*)d_in[7];
  const float* be     = (const float*)d_in[8];
  const float* A1     = (const float*)d_in[9];
  const float* A2     = (const float*)d_in[10];
  const float* A3     = (const float*)d_in[11];
  const float* bA1    = (const float*)d_in[12];
  const float* bA2    = (const float*)d_in[13];
  const float* bA3    = (const float*)d_in[14];
  const float* U      = (const float*)d_in[15];
  const float* V      = (const float*)d_in[16];
  const float* bU     = (const float*)d_in[17];
  const float* bV     = (const float*)d_in[18];
  const float* bnhg   = (const float*)d_in[19];
  const float* bnhb   = (const float*)d_in[20];
  const float* bneg   = (const float*)d_in[21];
  const float* bneb   = (const float*)d_in[22];
  const float* W1     = (const float*)d_in[23];
  const float* b1     = (const float*)d_in[24];
  const float* W2     = (const float*)d_in[25];
  const float* b2     = (const float*)d_in[26];

  const int N = in_sizes[0] / 512;
  const int E = in_sizes[1];

  float* fp = (float*)d_ws;
  float* hA   = fp; fp += (size_t)N * 64;
  float* hB   = fp; fp += (size_t)N * 64;
  float* hhat = fp; fp += (size_t)N * 64;
  float* XU   = fp; fp += (size_t)N * 64;
  float* sums = fp; fp += 1024;
  unsigned short* up = (unsigned short*)fp;
  unsigned short* e     = up; up += (size_t)E * 64;
  unsigned short* ehatA = up; up += (size_t)E * 64;
  unsigned short* ehatB = up; up += (size_t)E * 64;
  unsigned short* XA1 = up; up += (size_t)N * 64;
  unsigned short* XA2 = up; up += (size_t)N * 64;
  unsigned short* XV  = up; up += (size_t)N * 64;
  unsigned short* hb  = up; up += (size_t)N * 64;
  unsigned short* Wt  = up; up += 20 * 4096 + 12288;
  int* ip = (int*)up;
  int* order   = ip; ip += E;
  int* psrc    = ip; ip += E;
  int2* pedge  = (int2*)ip; ip += 2 * (size_t)E;
  int* cnt     = ip; ip += N;
  int* nxt     = ip; ip += N;
  int* row_ptr = ip; ip += N + 1;
  float* out = (float*)d_out;

  hipMemsetAsync(cnt, 0, sizeof(int) * N, stream);
  hipMemsetAsync(sums, 0, sizeof(float) * 1024, stream);
  k_hist<<<(E + 255) / 256, 256, 0, stream>>>(dst, cnt, E);
  k_prep<<<21, 256, 0, stream>>>(A1, A2, V, U, A3, W1, Wt);
  k_scan<<<1, 1024, 0, stream>>>(cnt, row_ptr, nxt, N, E);
  k_scatter<<<(E + 255) / 256, 256, 0, stream>>>(dst, src, nxt, order, psrc, pedge, E);

  const int ngroups = (N + 3) / 4;
  const int CG = ngroups < 1024 ? ngroups : 1024;  // 36 KB LDS -> 4 blocks/CU
  k_conv_mfma<<<CG, 256, 0, stream>>>(reads, conv_w, conv_b, hA, N);

  const int EPBLK = 1024;
  const int APBLK = 1024;
  const int NPB = 512;
  float* hin = hA;
  float* hout = hB;
  unsigned short* ehat_cur = ehatA;
  unsigned short* ehat_prev = ehatB;
  for (int l = 0; l < 4; ++l) {
    ehat_cur = (l & 1) ? ehatB : ehatA;
    ehat_prev = (l & 1) ? ehatA : ehatB;
    float* sums_e = sums + l * 128;
    float* sums_h = sums + 512 + l * 128;
    k_node_mfma<<<NPB, 256, 0, stream>>>(
        hin, (l > 0) ? hout : nullptr, hhat,
        (l > 0) ? (sums + 512 + (l - 1) * 128) : sums,
        bnhg + (l > 0 ? (l - 1) * 64 : 0), bnhb + (l > 0 ? (l - 1) * 64 : 0),
        Wt + l * 5 * 4096,
        bA1 + l * 64, bA2 + l * 64, bV + l * 64, bU + l * 64,
        XA1, XA2, XV, XU, N, l > 0 ? 1 : 0);
    if (l > 0) { float* t = hin; hin = hout; hout = t; }
    if (l == 0) {
      k_edge_mfma0<<<EPBLK, 256, 0, stream>>>(
          e, ehat_cur, sim, olen, order, We, be, pedge, XA1, XA2,
          Wt + 4 * 4096, bA3, sums_e, E);
    } else {
      k_edge_mfma<<<EPBLK, 256, 0, stream>>>(
          e, ehat_prev, ehat_cur, sums + (l - 1) * 128,
          bneg + (l - 1) * 64, bneb + (l - 1) * 64,
          pedge, XA1, XA2, Wt + (l * 5 + 4) * 4096, bA3 + l * 64, sums_e, E);
    }
    k_agg<<<APBLK, 256, 0, stream>>>(row_ptr, psrc, ehat_cur, XV, XU, hhat, sums_h, N);
  }

  k_update_h<<<(N * 16 + 255) / 256, 256, 0, stream>>>(
      hin, hb, hhat, sums + 512 + 3 * 128, bnhg + 3 * 64, bnhb + 3 * 64, N);
  k_decoder_mfma<<<EPBLK, 256, 0, stream>>>(
      hb, e, ehat_cur, sums + 3 * 128, bneg + 3 * 64, bneb + 3 * 64,
      pedge, order, Wt + 20 * 4096, b1, W2, b2, out, E);
}

// Round 15
// 754.240 us; speedup vs baseline: 1.0363x; 1.0363x over previous
//
#include <hip/hip_runtime.h>
#include <hip/hip_bf16.h>
#include <cstdint>
#include <cstddef>

#define DD 64

typedef __attribute__((ext_vector_type(8))) short short8;
typedef __attribute__((ext_vector_type(4))) float f32x4;

__device__ __forceinline__ float4 f4_0() { return make_float4(0.f, 0.f, 0.f, 0.f); }

__device__ __forceinline__ unsigned short f2bf(float f) {
  __hip_bfloat16 h = __float2bfloat16(f);
  return *reinterpret_cast<unsigned short*>(&h);
}
__device__ __forceinline__ float bfl(unsigned u) { return __uint_as_float(u << 16); }
__device__ __forceinline__ float bfh(unsigned u) { return __uint_as_float(u & 0xffff0000u); }
__device__ __forceinline__ float b2f(unsigned short u) {
  return __uint_as_float(((unsigned)u) << 16);
}

__device__ __forceinline__ short8 pack_bf16x8(float4 a, float4 b) {
  union { unsigned short us[8]; short8 v; } pk;
  pk.us[0] = f2bf(a.x); pk.us[1] = f2bf(a.y); pk.us[2] = f2bf(a.z); pk.us[3] = f2bf(a.w);
  pk.us[4] = f2bf(b.x); pk.us[5] = f2bf(b.y); pk.us[6] = f2bf(b.z); pk.us[7] = f2bf(b.w);
  return pk.v;
}

__device__ __forceinline__ short8 lds_frag(const unsigned short* p) {
  uint2 lo = *reinterpret_cast<const uint2*>(p);
  uint2 hi = *reinterpret_cast<const uint2*>(p + 4);
  union { unsigned u[4]; short8 v; } t;
  t.u[0] = lo.x; t.u[1] = lo.y; t.u[2] = hi.x; t.u[3] = hi.y;
  return t.v;
}
__device__ __forceinline__ short8 g_frag(const unsigned short* p) {
  return *reinterpret_cast<const short8*>(p);
}

// XCD-aware bijective block swizzle (gridDim.x divisible by 8).
__device__ __forceinline__ int xcd_vb() {
  return (blockIdx.x & 7) * (gridDim.x >> 3) + (blockIdx.x >> 3);
}

// ---------- CSR build ----------
__global__ __launch_bounds__(256) void k_hist(const int* __restrict__ dst,
                                              int* __restrict__ cnt, int E) {
  int j = blockIdx.x * 256 + threadIdx.x;
  if (j < E) atomicAdd(&cnt[dst[j]], 1);
}

__global__ __launch_bounds__(1024) void k_scan(const int* __restrict__ cnt,
                                               int* __restrict__ row_ptr,
                                               int* __restrict__ nxt, int N, int E) {
  __shared__ int wsum[16];
  __shared__ int carry_s;
  const int tid = threadIdx.x;
  const int wid = tid >> 6, lane = tid & 63;
  if (tid == 0) carry_s = 0;
  __syncthreads();
  const int ntl = (N + 4095) / 4096;
  for (int b = 0; b < ntl; ++b) {
    const int i0 = b * 4096 + tid * 4;
    int v0 = 0, v1 = 0, v2 = 0, v3 = 0;
    if (i0 + 3 < N) {
      int4 q = *reinterpret_cast<const int4*>(cnt + i0);
      v0 = q.x; v1 = q.y; v2 = q.z; v3 = q.w;
    } else {
      if (i0 < N) v0 = cnt[i0];
      if (i0 + 1 < N) v1 = cnt[i0 + 1];
      if (i0 + 2 < N) v2 = cnt[i0 + 2];
      if (i0 + 3 < N) v3 = cnt[i0 + 3];
    }
    const int tsum = v0 + v1 + v2 + v3;
    int x = tsum;
#pragma unroll
    for (int off = 1; off < 64; off <<= 1) {
      int y = __shfl_up(x, off, 64);
      if (lane >= off) x += y;
    }
    if (lane == 63) wsum[wid] = x;
    __syncthreads();
    if (wid == 0 && lane < 16) {
      int wv = wsum[lane];
#pragma unroll
      for (int off = 1; off < 16; off <<= 1) {
        int y = __shfl_up(wv, off, 64);
        if (lane >= off) wv += y;
      }
      wsum[lane] = wv;
    }
    __syncthreads();
    int base = carry_s + (wid > 0 ? wsum[wid - 1] : 0) + (x - tsum);
    int e1 = base + v0, e2 = e1 + v1, e3 = e2 + v2;
    if (i0 < N) { row_ptr[i0] = base; nxt[i0] = base; }
    if (i0 + 1 < N) { row_ptr[i0 + 1] = e1; nxt[i0 + 1] = e1; }
    if (i0 + 2 < N) { row_ptr[i0 + 2] = e2; nxt[i0 + 2] = e2; }
    if (i0 + 3 < N) { row_ptr[i0 + 3] = e3; nxt[i0 + 3] = e3; }
    __syncthreads();
    if (tid == 0) carry_s += wsum[15];
    __syncthreads();
  }
  if (tid == 0) row_ptr[N] = E;
}

__global__ __launch_bounds__(256) void k_scatter(const int* __restrict__ dst,
                                                 const int* __restrict__ src,
                                                 int* __restrict__ nxt,
                                                 int* __restrict__ order,
                                                 int* __restrict__ psrc,
                                                 int2* __restrict__ pedge, int E) {
  int j = blockIdx.x * 256 + threadIdx.x;
  if (j >= E) return;
  int d = dst[j];
  int s = src[j];
  int pos = atomicAdd(&nxt[d], 1);
  order[pos] = j;
  psrc[pos] = s;
  pedge[pos] = make_int2(s, d);
}

// ---------- weight pre-transpose to bf16 ----------
__global__ __launch_bounds__(256) void k_prep(const float* __restrict__ A1,
                                              const float* __restrict__ A2,
                                              const float* __restrict__ V,
                                              const float* __restrict__ U,
                                              const float* __restrict__ A3,
                                              const float* __restrict__ W1,
                                              unsigned short* __restrict__ T) {
  const int b = blockIdx.x;
  const int tid = threadIdx.x;
  if (b < 20) {
    const int l = b / 5, m = b % 5;
    const float* srcp =
        (m == 0 ? A1 : m == 1 ? A2 : m == 2 ? V : m == 3 ? U : A3) + l * 4096;
    unsigned short* dstp = T + b * 4096;
    for (int i = tid; i < 4096; i += 256) {
      int n = i >> 6, k = i & 63;
      dstp[i] = f2bf(srcp[k * 64 + n]);
    }
  } else {
    unsigned short* dstp = T + 20 * 4096;
    for (int i = tid; i < 12288; i += 256) {
      int n = i / 192, k = i % 192;
      dstp[i] = f2bf(W1[k * 64 + n]);
    }
  }
}

// ---------- conv staging helpers ----------
struct ConvRegs { float4 v[3][2]; };

__device__ __forceinline__ void conv_load(const float* __restrict__ reads, int N,
                                          int g, int tid, ConvRegs& R) {
#pragma unroll
  for (int it = 0; it < 3; ++it) {
    const int task = tid + it * 256;
    R.v[it][0] = f4_0(); R.v[it][1] = f4_0();
    if (task < 576) {
      const int node = task / 144, rem = task % 144;
      const int c = rem / 36, u = rem % 36;
      const int gn = g * 4 + node;
      if (gn < N) {
        const float* rp = reads + (size_t)gn * 512 + c * 128 + 4 * u;
        if (u <= 31) R.v[it][0] = *reinterpret_cast<const float4*>(rp);
        if (u <= 30) R.v[it][1] = *reinterpret_cast<const float4*>(rp + 4);
      }
    }
  }
}

__device__ __forceinline__ void conv_write(unsigned short* __restrict__ cbuf,
                                           int tid, const ConvRegs& R) {
#pragma unroll
  for (int it = 0; it < 3; ++it) {
    const int task = tid + it * 256;
    if (task < 576) {
      const int node = task / 144, rem = task % 144;
      const int c = rem / 36, u = rem % 36;
      const float4 v0 = R.v[it][0], v1 = R.v[it][1];
      unsigned pk0, pk1, pk2, pk3;
      asm("v_cvt_pk_bf16_f32 %0, %1, %2" : "=v"(pk0) : "v"(v0.x), "v"(v0.y));
      asm("v_cvt_pk_bf16_f32 %0, %1, %2" : "=v"(pk1) : "v"(v0.z), "v"(v0.w));
      asm("v_cvt_pk_bf16_f32 %0, %1, %2" : "=v"(pk2) : "v"(v1.x), "v"(v1.y));
      asm("v_cvt_pk_bf16_f32 %0, %1, %2" : "=v"(pk3) : "v"(v1.z), "v"(v1.w));
      const unsigned a0 = __builtin_amdgcn_alignbit(pk1, pk0, 16);
      const unsigned a1 = __builtin_amdgcn_alignbit(pk2, pk1, 16);
      const unsigned a2 = __builtin_amdgcn_alignbit(pk3, pk2, 16);
      const int base = ((node * 4 + c) * 4) * 144 + 4 * u;
      *reinterpret_cast<uint2*>(&cbuf[base + 0 * 144]) = make_uint2(pk0, pk1);
      *reinterpret_cast<uint2*>(&cbuf[base + 1 * 144]) = make_uint2(a0, a1);
      *reinterpret_cast<uint2*>(&cbuf[base + 2 * 144]) = make_uint2(pk1, pk2);
      *reinterpret_cast<uint2*>(&cbuf[base + 3 * 144]) = make_uint2(a1, a2);
    }
  }
}

// ---------- conv1d + maxpool: persistent, double-buffered LDS staging ----------
__global__ __launch_bounds__(256) void k_conv_mfma(const float* __restrict__ reads,
                                                   const float* __restrict__ w,
                                                   const float* __restrict__ bias,
                                                   float* __restrict__ h, int N) {
  __shared__ unsigned short cp[2][4 * 4 * 4 * 144];  // double buffer, 36 KB
  const int tid = threadIdx.x;
  const int wid = tid >> 6, lane = tid & 63;
  const int col = lane & 15, grp = lane >> 4;
  const int ngroups = (N + 3) / 4;
  if ((int)blockIdx.x >= ngroups) return;
  short8 wf[4][2];
#pragma unroll
  for (int nt = 0; nt < 4; ++nt)
#pragma unroll
    for (int ks = 0; ks < 2; ++ks) {
      const int d = nt * 16 + col;
      const int kb = ks * 32 + grp * 8;
      const float* wp = w + d * 64 + kb;
      float4 w0 = *reinterpret_cast<const float4*>(wp);
      float4 w1 = *reinterpret_cast<const float4*>(wp + 4);
      wf[nt][ks] = pack_bf16x8(w0, w1);
    }
  ConvRegs RA, RB;
  conv_load(reads, N, blockIdx.x, tid, RA);
  int p = 0;
  const int s = col & 3;
  for (int g = blockIdx.x; g < ngroups; g += gridDim.x) {
    conv_write(&cp[p][0], tid, RA);
    const int gnext = g + gridDim.x;
    if (gnext < ngroups) conv_load(reads, N, gnext, tid, RB);
    __syncthreads();
    const int gn = g * 4 + wid;
    if (gn < N) {
      const unsigned short* cbuf = &cp[p][0];
      float vmax[4];
#pragma unroll
      for (int nt = 0; nt < 4; ++nt) vmax[nt] = -3.0e38f;
      for (int mt = 0; mt < 8; ++mt) {
        const int t = mt * 16 + col;
        short8 af[2];
#pragma unroll
        for (int ks = 0; ks < 2; ++ks) {
          const int kbase = ks * 32 + grp * 8;
          const int c = kbase >> 4;
          const int kk0 = kbase & 15;
          const int q = (t - s) + kk0;
          af[ks] = lds_frag(&cbuf[((wid * 4 + c) * 4 + s) * 144 + q]);
        }
        f32x4 acc[4] = {};
#pragma unroll
        for (int ks = 0; ks < 2; ++ks)
#pragma unroll
          for (int nt = 0; nt < 4; ++nt)
            acc[nt] = __builtin_amdgcn_mfma_f32_16x16x32_bf16(af[ks], wf[nt][ks], acc[nt], 0, 0, 0);
        if (mt < 7) {
#pragma unroll
          for (int nt = 0; nt < 4; ++nt)
#pragma unroll
            for (int r = 0; r < 4; ++r) vmax[nt] = fmaxf(vmax[nt], acc[nt][r]);
        } else {
          if (grp == 0) {
#pragma unroll
            for (int nt = 0; nt < 4; ++nt) vmax[nt] = fmaxf(vmax[nt], acc[nt][0]);
          }
        }
      }
#pragma unroll
      for (int off = 16; off <= 32; off <<= 1)
#pragma unroll
        for (int nt = 0; nt < 4; ++nt)
          vmax[nt] = fmaxf(vmax[nt], __shfl_xor(vmax[nt], off, 64));
      if (grp == 0) {
#pragma unroll
        for (int nt = 0; nt < 4; ++nt) {
          const int d = nt * 16 + col;
          h[(size_t)gn * 64 + d] = vmax[nt] + bias[d];
        }
      }
    }
    p ^= 1;
    RA = RB;
  }
}

// ---------- persistent node MFMA: fused h-update + 4 GEMMs ----------
__global__ __launch_bounds__(256) void k_node_mfma(const float* __restrict__ h_in,
                                                   float* __restrict__ h_out,
                                                   const float* __restrict__ hhat,
                                                   const float* __restrict__ sums_prev,
                                                   const float* __restrict__ gam,
                                                   const float* __restrict__ bet,
                                                   const unsigned short* __restrict__ Wt4,
                                                   const float* __restrict__ bA1,
                                                   const float* __restrict__ bA2,
                                                   const float* __restrict__ bV,
                                                   const float* __restrict__ bU,
                                                   unsigned short* __restrict__ XA1,
                                                   unsigned short* __restrict__ XA2,
                                                   unsigned short* __restrict__ XV,
                                                   float* __restrict__ XU,
                                                   int N, int hasupd) {
  __shared__ float s_coef[128];
  const int tid = threadIdx.x;
  if (hasupd) {
    if (tid < 64) {
      const float invR = 1.f / (float)N;
      float mean = sums_prev[tid] * invR;
      float var = sums_prev[64 + tid] * invR - mean * mean;
      float sc = gam[tid] * rsqrtf(var + 1e-5f);
      s_coef[tid] = sc;
      s_coef[64 + tid] = bet[tid] - mean * sc;
    }
    __syncthreads();
  }
  const int wid = tid >> 6, lane = tid & 63;
  const int col = lane & 15, g = lane >> 4;
  const int ntiles = (N + 15) / 16;
  for (int tw = blockIdx.x * 4 + wid; tw < ntiles; tw += gridDim.x * 4) {
    int n = tw * 16 + col;
    const bool valid = n < N;
    if (!valid) n = N - 1;
    short8 bfr[2];
#pragma unroll
    for (int ks = 0; ks < 2; ++ks) {
      const int c0 = ks * 32 + g * 8;
      const float* hp = h_in + (size_t)n * 64 + c0;
      float4 x0 = *reinterpret_cast<const float4*>(hp);
      float4 x1 = *reinterpret_cast<const float4*>(hp + 4);
      if (hasupd) {
        const float* yp = hhat + (size_t)n * 64 + c0;
        float4 y0 = *reinterpret_cast<const float4*>(yp);
        float4 y1 = *reinterpret_cast<const float4*>(yp + 4);
        float4 sc0 = *reinterpret_cast<const float4*>(&s_coef[c0]);
        float4 sc1 = *reinterpret_cast<const float4*>(&s_coef[c0 + 4]);
        float4 sh0 = *reinterpret_cast<const float4*>(&s_coef[64 + c0]);
        float4 sh1 = *reinterpret_cast<const float4*>(&s_coef[64 + c0 + 4]);
        x0.x += fmaxf(fmaf(sc0.x, y0.x, sh0.x), 0.f);
        x0.y += fmaxf(fmaf(sc0.y, y0.y, sh0.y), 0.f);
        x0.z += fmaxf(fmaf(sc0.z, y0.z, sh0.z), 0.f);
        x0.w += fmaxf(fmaf(sc0.w, y0.w, sh0.w), 0.f);
        x1.x += fmaxf(fmaf(sc1.x, y1.x, sh1.x), 0.f);
        x1.y += fmaxf(fmaf(sc1.y, y1.y, sh1.y), 0.f);
        x1.z += fmaxf(fmaf(sc1.z, y1.z, sh1.z), 0.f);
        x1.w += fmaxf(fmaf(sc1.w, y1.w, sh1.w), 0.f);
        if (valid) {
          float* op = h_out + (size_t)n * 64 + c0;
          *reinterpret_cast<float4*>(op) = x0;
          *reinterpret_cast<float4*>(op + 4) = x1;
        }
      }
      bfr[ks] = pack_bf16x8(x0, x1);
    }
#pragma unroll
    for (int m = 0; m < 4; ++m) {
      const unsigned short* Wm = Wt4 + m * 4096;
      f32x4 acc[4] = {};
#pragma unroll
      for (int ks = 0; ks < 2; ++ks) {
        const int ko = ks * 32 + g * 8;
#pragma unroll
        for (int mt = 0; mt < 4; ++mt) {
          short8 aa = g_frag(Wm + (mt * 16 + col) * 64 + ko);
          acc[mt] = __builtin_amdgcn_mfma_f32_16x16x32_bf16(aa, bfr[ks], acc[mt], 0, 0, 0);
        }
      }
      if (!valid) continue;
      const float* bb = (m == 0) ? bA1 : (m == 1) ? bA2 : (m == 2) ? bV : bU;
#pragma unroll
      for (int mt = 0; mt < 4; ++mt) {
        const int chb = mt * 16 + g * 4;
        float4 bv = *reinterpret_cast<const float4*>(bb + chb);
        float o0 = acc[mt][0] + bv.x;
        float o1 = acc[mt][1] + bv.y;
        float o2 = acc[mt][2] + bv.z;
        float o3 = acc[mt][3] + bv.w;
        if (m < 3) {
          unsigned short* X = (m == 0) ? XA1 : (m == 1) ? XA2 : XV;
          ushort4 ov;
          ov.x = f2bf(o0); ov.y = f2bf(o1); ov.z = f2bf(o2); ov.w = f2bf(o3);
          *reinterpret_cast<ushort4*>(X + (size_t)n * 64 + chb) = ov;
        } else {
          *reinterpret_cast<float4*>(XU + (size_t)n * 64 + chb) =
              make_float4(o0, o1, o2, o3);
        }
      }
    }
  }
}

// ---------- layer-0 edge MFMA: fused edge-encoder + BN stats; prefetched; XCD swizzle ----------
__global__ __launch_bounds__(256) void k_edge_mfma0(unsigned short* __restrict__ e,
                                                    unsigned short* __restrict__ ehat_out,
                                                    const float* __restrict__ sim,
                                                    const float* __restrict__ olen,
                                                    const int* __restrict__ order,
                                                    const float* __restrict__ We,
                                                    const float* __restrict__ be,
                                                    const int2* __restrict__ pedge,
                                                    const unsigned short* __restrict__ XA1,
                                                    const unsigned short* __restrict__ XA2,
                                                    const unsigned short* __restrict__ A3t,
                                                    const float* __restrict__ bA3,
                                                    float* __restrict__ sums_out, int E) {
  __shared__ float s_sums[128];
  const int tid = threadIdx.x;
  if (tid < 128) s_sums[tid] = 0.f;
  __syncthreads();
  const int wid = tid >> 6, lane = tid & 63;
  const int col = lane & 15, g = lane >> 4;
  float4 ba[4];
#pragma unroll
  for (int mt = 0; mt < 4; ++mt)
    ba[mt] = *reinterpret_cast<const float4*>(bA3 + mt * 16 + g * 4);
  float4 w0[2][2], w1[2][2], bev[2][2];
#pragma unroll
  for (int ks = 0; ks < 2; ++ks) {
    const int c0 = ks * 32 + g * 8;
    w0[ks][0] = *reinterpret_cast<const float4*>(We + c0);
    w0[ks][1] = *reinterpret_cast<const float4*>(We + c0 + 4);
    w1[ks][0] = *reinterpret_cast<const float4*>(We + 64 + c0);
    w1[ks][1] = *reinterpret_cast<const float4*>(We + 64 + c0 + 4);
    bev[ks][0] = *reinterpret_cast<const float4*>(be + c0);
    bev[ks][1] = *reinterpret_cast<const float4*>(be + c0 + 4);
  }
  float statS[16], statQ[16];
#pragma unroll
  for (int i = 0; i < 16; ++i) { statS[i] = 0.f; statQ[i] = 0.f; }
  const int ntiles = (E + 15) / 16;
  const int stride = gridDim.x * 4;
  int tw = xcd_vb() * 4 + wid;
  int2 idx_n = make_int2(0, 0);
  int oe_n = 0;
  if (tw < ntiles) {
    int p = tw * 16 + col; if (p >= E) p = E - 1;
    idx_n = pedge[p];
    oe_n = order[p];
  }
  for (; tw < ntiles; tw += stride) {
    int p = tw * 16 + col;
    const bool valid = p < E;
    if (!valid) p = E - 1;
    const int se = idx_n.x, de = idx_n.y;
    const float sv = sim[oe_n], lv = olen[oe_n];
    ushort4 gx1[4], gx2[4];
#pragma unroll
    for (int mt = 0; mt < 4; ++mt) {
      const int chb = mt * 16 + g * 4;
      gx1[mt] = *reinterpret_cast<const ushort4*>(XA1 + (size_t)se * 64 + chb);
      gx2[mt] = *reinterpret_cast<const ushort4*>(XA2 + (size_t)de * 64 + chb);
    }
    const int twn = tw + stride;
    if (twn < ntiles) {
      int pn = twn * 16 + col; if (pn >= E) pn = E - 1;
      idx_n = pedge[pn];
      oe_n = order[pn];
    }
    short8 bfr[2];
#pragma unroll
    for (int ks = 0; ks < 2; ++ks) {
      float4 e0, e1;
      e0.x = fmaf(sv, w0[ks][0].x, fmaf(lv, w1[ks][0].x, bev[ks][0].x));
      e0.y = fmaf(sv, w0[ks][0].y, fmaf(lv, w1[ks][0].y, bev[ks][0].y));
      e0.z = fmaf(sv, w0[ks][0].z, fmaf(lv, w1[ks][0].z, bev[ks][0].z));
      e0.w = fmaf(sv, w0[ks][0].w, fmaf(lv, w1[ks][0].w, bev[ks][0].w));
      e1.x = fmaf(sv, w0[ks][1].x, fmaf(lv, w1[ks][1].x, bev[ks][1].x));
      e1.y = fmaf(sv, w0[ks][1].y, fmaf(lv, w1[ks][1].y, bev[ks][1].y));
      e1.z = fmaf(sv, w0[ks][1].z, fmaf(lv, w1[ks][1].z, bev[ks][1].z));
      e1.w = fmaf(sv, w0[ks][1].w, fmaf(lv, w1[ks][1].w, bev[ks][1].w));
      bfr[ks] = pack_bf16x8(e0, e1);
      if (valid)
        *reinterpret_cast<short8*>(e + (size_t)p * 64 + ks * 32 + g * 8) = bfr[ks];
    }
    f32x4 acc[4] = {};
#pragma unroll
    for (int ks = 0; ks < 2; ++ks)
#pragma unroll
      for (int mt = 0; mt < 4; ++mt) {
        short8 aa = g_frag(A3t + (mt * 16 + col) * 64 + ks * 32 + g * 8);
        acc[mt] = __builtin_amdgcn_mfma_f32_16x16x32_bf16(aa, bfr[ks], acc[mt], 0, 0, 0);
      }
    if (valid) {
#pragma unroll
      for (int mt = 0; mt < 4; ++mt) {
        const int chb = mt * 16 + g * 4;
        float o0 = acc[mt][0] + b2f(gx1[mt].x) + b2f(gx2[mt].x) + ba[mt].x;
        float o1 = acc[mt][1] + b2f(gx1[mt].y) + b2f(gx2[mt].y) + ba[mt].y;
        float o2 = acc[mt][2] + b2f(gx1[mt].z) + b2f(gx2[mt].z) + ba[mt].z;
        float o3 = acc[mt][3] + b2f(gx1[mt].w) + b2f(gx2[mt].w) + ba[mt].w;
        ushort4 ov;
        ov.x = f2bf(o0); ov.y = f2bf(o1); ov.z = f2bf(o2); ov.w = f2bf(o3);
        *reinterpret_cast<ushort4*>(ehat_out + (size_t)p * 64 + chb) = ov;
        statS[mt * 4 + 0] += o0; statQ[mt * 4 + 0] = fmaf(o0, o0, statQ[mt * 4 + 0]);
        statS[mt * 4 + 1] += o1; statQ[mt * 4 + 1] = fmaf(o1, o1, statQ[mt * 4 + 1]);
        statS[mt * 4 + 2] += o2; statQ[mt * 4 + 2] = fmaf(o2, o2, statQ[mt * 4 + 2]);
        statS[mt * 4 + 3] += o3; statQ[mt * 4 + 3] = fmaf(o3, o3, statQ[mt * 4 + 3]);
      }
    }
  }
#pragma unroll
  for (int off = 1; off <= 8; off <<= 1)
#pragma unroll
    for (int i = 0; i < 16; ++i) {
      statS[i] += __shfl_xor(statS[i], off, 64);
      statQ[i] += __shfl_xor(statQ[i], off, 64);
    }
  if (col == 0) {
#pragma unroll
    for (int mt = 0; mt < 4; ++mt)
#pragma unroll
      for (int c = 0; c < 4; ++c) {
        const int ch = mt * 16 + g * 4 + c;
        atomicAdd(&s_sums[ch], statS[mt * 4 + c]);
        atomicAdd(&s_sums[64 + ch], statQ[mt * 4 + c]);
      }
  }
  __syncthreads();
  if (tid < 128) atomicAdd(&sums_out[tid], s_sums[tid]);
}

// ---------- layers 1..3 edge MFMA: prefetched streams, fused e-update + BN stats; XCD swizzle ----------
__global__ __launch_bounds__(256) void k_edge_mfma(unsigned short* __restrict__ e,
                                                   const unsigned short* __restrict__ ehat_prev,
                                                   unsigned short* __restrict__ ehat_out,
                                                   const float* __restrict__ sums_prev,
                                                   const float* __restrict__ gprev,
                                                   const float* __restrict__ bprev,
                                                   const int2* __restrict__ pedge,
                                                   const unsigned short* __restrict__ XA1,
                                                   const unsigned short* __restrict__ XA2,
                                                   const unsigned short* __restrict__ A3t,
                                                   const float* __restrict__ bA3,
                                                   float* __restrict__ sums_out, int E) {
  __shared__ float s_coef[128];
  __shared__ float s_sums[128];
  const int tid = threadIdx.x;
  if (tid < 128) s_sums[tid] = 0.f;
  if (tid < 64) {
    float mean = sums_prev[tid] / (float)E;
    float var = sums_prev[64 + tid] / (float)E - mean * mean;
    float sc = gprev[tid] * rsqrtf(var + 1e-5f);
    s_coef[tid] = sc;
    s_coef[64 + tid] = bprev[tid] - mean * sc;
  }
  __syncthreads();
  const int wid = tid >> 6, lane = tid & 63;
  const int col = lane & 15, g = lane >> 4;
  float4 ba[4];
#pragma unroll
  for (int mt = 0; mt < 4; ++mt)
    ba[mt] = *reinterpret_cast<const float4*>(bA3 + mt * 16 + g * 4);
  float statS[16], statQ[16];
#pragma unroll
  for (int i = 0; i < 16; ++i) { statS[i] = 0.f; statQ[i] = 0.f; }
  const int ntiles = (E + 15) / 16;
  const int stride = gridDim.x * 4;
  int tw = xcd_vb() * 4 + wid;
  int2 idx_n = make_int2(0, 0);
  uint4 eo_n0 = {}, eo_n1 = {}, hv_n0 = {}, hv_n1 = {};
  if (tw < ntiles) {
    int p = tw * 16 + col; if (p >= E) p = E - 1;
    idx_n = pedge[p];
    const unsigned short* ep = e + (size_t)p * 64 + g * 8;
    eo_n0 = *reinterpret_cast<const uint4*>(ep);
    eo_n1 = *reinterpret_cast<const uint4*>(ep + 32);
    const unsigned short* hp = ehat_prev + (size_t)p * 64 + g * 8;
    hv_n0 = *reinterpret_cast<const uint4*>(hp);
    hv_n1 = *reinterpret_cast<const uint4*>(hp + 32);
  }
  for (; tw < ntiles; tw += stride) {
    int p = tw * 16 + col;
    const bool valid = p < E;
    if (!valid) p = E - 1;
    const int se = idx_n.x, de = idx_n.y;
    const uint4 eoc[2] = {eo_n0, eo_n1};
    const uint4 hvc[2] = {hv_n0, hv_n1};
    ushort4 gx1[4], gx2[4];
#pragma unroll
    for (int mt = 0; mt < 4; ++mt) {
      const int chb = mt * 16 + g * 4;
      gx1[mt] = *reinterpret_cast<const ushort4*>(XA1 + (size_t)se * 64 + chb);
      gx2[mt] = *reinterpret_cast<const ushort4*>(XA2 + (size_t)de * 64 + chb);
    }
    const int twn = tw + stride;
    if (twn < ntiles) {
      int pn = twn * 16 + col; if (pn >= E) pn = E - 1;
      idx_n = pedge[pn];
      const unsigned short* ep = e + (size_t)pn * 64 + g * 8;
      eo_n0 = *reinterpret_cast<const uint4*>(ep);
      eo_n1 = *reinterpret_cast<const uint4*>(ep + 32);
      const unsigned short* hp = ehat_prev + (size_t)pn * 64 + g * 8;
      hv_n0 = *reinterpret_cast<const uint4*>(hp);
      hv_n1 = *reinterpret_cast<const uint4*>(hp + 32);
    }
    short8 bfr[2];
#pragma unroll
    for (int ks = 0; ks < 2; ++ks) {
      const int c0 = ks * 32 + g * 8;
      const uint4 eo = eoc[ks];
      const uint4 hv = hvc[ks];
      float4 e0 = make_float4(bfl(eo.x), bfh(eo.x), bfl(eo.y), bfh(eo.y));
      float4 e1 = make_float4(bfl(eo.z), bfh(eo.z), bfl(eo.w), bfh(eo.w));
      float4 sc0 = *reinterpret_cast<const float4*>(&s_coef[c0]);
      float4 sc1 = *reinterpret_cast<const float4*>(&s_coef[c0 + 4]);
      float4 sh0 = *reinterpret_cast<const float4*>(&s_coef[64 + c0]);
      float4 sh1 = *reinterpret_cast<const float4*>(&s_coef[64 + c0 + 4]);
      e0.x += fmaxf(fmaf(sc0.x, bfl(hv.x), sh0.x), 0.f);
      e0.y += fmaxf(fmaf(sc0.y, bfh(hv.x), sh0.y), 0.f);
      e0.z += fmaxf(fmaf(sc0.z, bfl(hv.y), sh0.z), 0.f);
      e0.w += fmaxf(fmaf(sc0.w, bfh(hv.y), sh0.w), 0.f);
      e1.x += fmaxf(fmaf(sc1.x, bfl(hv.z), sh1.x), 0.f);
      e1.y += fmaxf(fmaf(sc1.y, bfh(hv.z), sh1.y), 0.f);
      e1.z += fmaxf(fmaf(sc1.z, bfl(hv.w), sh1.z), 0.f);
      e1.w += fmaxf(fmaf(sc1.w, bfh(hv.w), sh1.w), 0.f);
      bfr[ks] = pack_bf16x8(e0, e1);
      if (valid)
        *reinterpret_cast<short8*>(e + (size_t)p * 64 + c0) = bfr[ks];
    }
    f32x4 acc[4] = {};
#pragma unroll
    for (int ks = 0; ks < 2; ++ks)
#pragma unroll
      for (int mt = 0; mt < 4; ++mt) {
        short8 aa = g_frag(A3t + (mt * 16 + col) * 64 + ks * 32 + g * 8);
        acc[mt] = __builtin_amdgcn_mfma_f32_16x16x32_bf16(aa, bfr[ks], acc[mt], 0, 0, 0);
      }
    if (valid) {
#pragma unroll
      for (int mt = 0; mt < 4; ++mt) {
        const int chb = mt * 16 + g * 4;
        float o0 = acc[mt][0] + b2f(gx1[mt].x) + b2f(gx2[mt].x) + ba[mt].x;
        float o1 = acc[mt][1] + b2f(gx1[mt].y) + b2f(gx2[mt].y) + ba[mt].y;
        float o2 = acc[mt][2] + b2f(gx1[mt].z) + b2f(gx2[mt].z) + ba[mt].z;
        float o3 = acc[mt][3] + b2f(gx1[mt].w) + b2f(gx2[mt].w) + ba[mt].w;
        ushort4 ov;
        ov.x = f2bf(o0); ov.y = f2bf(o1); ov.z = f2bf(o2); ov.w = f2bf(o3);
        *reinterpret_cast<ushort4*>(ehat_out + (size_t)p * 64 + chb) = ov;
        statS[mt * 4 + 0] += o0; statQ[mt * 4 + 0] = fmaf(o0, o0, statQ[mt * 4 + 0]);
        statS[mt * 4 + 1] += o1; statQ[mt * 4 + 1] = fmaf(o1, o1, statQ[mt * 4 + 1]);
        statS[mt * 4 + 2] += o2; statQ[mt * 4 + 2] = fmaf(o2, o2, statQ[mt * 4 + 2]);
        statS[mt * 4 + 3] += o3; statQ[mt * 4 + 3] = fmaf(o3, o3, statQ[mt * 4 + 3]);
      }
    }
  }
#pragma unroll
  for (int off = 1; off <= 8; off <<= 1)
#pragma unroll
    for (int i = 0; i < 16; ++i) {
      statS[i] += __shfl_xor(statS[i], off, 64);
      statQ[i] += __shfl_xor(statQ[i], off, 64);
    }
  if (col == 0) {
#pragma unroll
    for (int mt = 0; mt < 4; ++mt)
#pragma unroll
      for (int c = 0; c < 4; ++c) {
        const int ch = mt * 16 + g * 4 + c;
        atomicAdd(&s_sums[ch], statS[mt * 4 + c]);
        atomicAdd(&s_sums[64 + ch], statQ[mt * 4 + c]);
      }
  }
  __syncthreads();
  if (tid < 128) atomicAdd(&sums_out[tid], s_sums[tid]);
}

// ---------- aggregation + hhat + fused h-stats (XCD swizzle) ----------
__global__ __launch_bounds__(256) void k_agg(const int* __restrict__ row_ptr,
                                             const int* __restrict__ psrc,
                                             const unsigned short* __restrict__ ehat,
                                             const unsigned short* __restrict__ XV,
                                             const float* __restrict__ XU,
                                             float* __restrict__ hhat,
                                             float* __restrict__ sums_h, int N) {
  __shared__ float s_sums[128];
  const int tid = threadIdx.x;
  if (tid < 128) s_sums[tid] = 0.f;
  __syncthreads();
  float sS[4] = {0.f, 0.f, 0.f, 0.f}, sQ[4] = {0.f, 0.f, 0.f, 0.f};
  const int total = N * 16;
  for (int idx = xcd_vb() * 256 + tid; idx < total; idx += gridDim.x * 256) {
    int n = idx >> 4, dc = (idx & 15) << 2;
    int beg = row_ptr[n], end = row_ptr[n + 1];
    float4 nm = f4_0(), dn = f4_0();
    for (int i = beg; i < end; ++i) {
      int sj = psrc[i];
      uint2 ev = *reinterpret_cast<const uint2*>(ehat + (size_t)i * 64 + dc);
      uint2 vv = *reinterpret_cast<const uint2*>(XV + (size_t)sj * 64 + dc);
      float s0 = 1.f / (1.f + __expf(-bfl(ev.x)));
      float s1 = 1.f / (1.f + __expf(-bfh(ev.x)));
      float s2 = 1.f / (1.f + __expf(-bfl(ev.y)));
      float s3 = 1.f / (1.f + __expf(-bfh(ev.y)));
      dn.x += s0; dn.y += s1; dn.z += s2; dn.w += s3;
      nm.x = fmaf(s0, bfl(vv.x), nm.x);
      nm.y = fmaf(s1, bfh(vv.x), nm.y);
      nm.z = fmaf(s2, bfl(vv.y), nm.z);
      nm.w = fmaf(s3, bfh(vv.y), nm.w);
    }
    float4 xu = *reinterpret_cast<const float4*>(XU + (size_t)n * 64 + dc);
    float h0 = xu.x + nm.x / (dn.x + 1e-6f);
    float h1 = xu.y + nm.y / (dn.y + 1e-6f);
    float h2 = xu.z + nm.z / (dn.z + 1e-6f);
    float h3 = xu.w + nm.w / (dn.w + 1e-6f);
    *reinterpret_cast<float4*>(hhat + (size_t)n * 64 + dc) = make_float4(h0, h1, h2, h3);
    sS[0] += h0; sQ[0] = fmaf(h0, h0, sQ[0]);
    sS[1] += h1; sQ[1] = fmaf(h1, h1, sQ[1]);
    sS[2] += h2; sQ[2] = fmaf(h2, h2, sQ[2]);
    sS[3] += h3; sQ[3] = fmaf(h3, h3, sQ[3]);
  }
#pragma unroll
  for (int off = 16; off <= 32; off <<= 1)
#pragma unroll
    for (int c = 0; c < 4; ++c) {
      sS[c] += __shfl_xor(sS[c], off, 64);
      sQ[c] += __shfl_xor(sQ[c], off, 64);
    }
  const int lane = tid & 63;
  if (lane < 16) {
    const int dc = lane << 2;
#pragma unroll
    for (int c = 0; c < 4; ++c) {
      atomicAdd(&s_sums[dc + c], sS[c]);
      atomicAdd(&s_sums[64 + dc + c], sQ[c]);
    }
  }
  __syncthreads();
  if (tid < 128) atomicAdd(&sums_h[tid], s_sums[tid]);
}

// ---------- final h-update: h += relu(BN(hhat)); also writes bf16 copy ----------
__global__ __launch_bounds__(256) void k_update_h(float* __restrict__ h,
                                                  unsigned short* __restrict__ hb,
                                                  const float* __restrict__ hhat,
                                                  const float* __restrict__ sums,
                                                  const float* __restrict__ gamma,
                                                  const float* __restrict__ beta, int R) {
  int idx = blockIdx.x * 256 + threadIdx.x;
  if (idx >= R * 16) return;
  int r = idx >> 4, dc = (idx & 15) << 2;
  const float invR = 1.f / (float)R;
  float4 sv = *reinterpret_cast<const float4*>(sums + dc);
  float4 qv = *reinterpret_cast<const float4*>(sums + 64 + dc);
  float4 gm = *reinterpret_cast<const float4*>(gamma + dc);
  float4 bt = *reinterpret_cast<const float4*>(beta + dc);
  float m0 = sv.x * invR, m1 = sv.y * invR, m2 = sv.z * invR, m3 = sv.w * invR;
  float c0 = gm.x * rsqrtf(qv.x * invR - m0 * m0 + 1e-5f);
  float c1 = gm.y * rsqrtf(qv.y * invR - m1 * m1 + 1e-5f);
  float c2 = gm.z * rsqrtf(qv.z * invR - m2 * m2 + 1e-5f);
  float c3 = gm.w * rsqrtf(qv.w * invR - m3 * m3 + 1e-5f);
  float h0 = bt.x - m0 * c0, h1 = bt.y - m1 * c1, h2 = bt.z - m2 * c2, h3 = bt.w - m3 * c3;
  size_t off = (size_t)r * 64 + dc;
  float4 y = *reinterpret_cast<const float4*>(hhat + off);
  float4 x = *reinterpret_cast<const float4*>(h + off);
  x.x += fmaxf(fmaf(c0, y.x, h0), 0.f);
  x.y += fmaxf(fmaf(c1, y.y, h1), 0.f);
  x.z += fmaxf(fmaf(c2, y.z, h2), 0.f);
  x.w += fmaxf(fmaf(c3, y.w, h3), 0.f);
  *reinterpret_cast<float4*>(h + off) = x;
  ushort4 hv;
  hv.x = f2bf(x.x); hv.y = f2bf(x.y); hv.z = f2bf(x.z); hv.w = f2bf(x.w);
  *reinterpret_cast<ushort4*>(hb + off) = hv;
}

// ---------- persistent decoder MFMA; bf16 h gathers, prefetched streams, XCD swizzle ----------
__global__ __launch_bounds__(256) void k_decoder_mfma(const unsigned short* __restrict__ hb,
                                                      const unsigned short* __restrict__ e,
                                                      const unsigned short* __restrict__ ehat3,
                                                      const float* __restrict__ sums_e3,
                                                      const float* __restrict__ ge3,
                                                      const float* __restrict__ be3,
                                                      const int2* __restrict__ pedge,
                                                      const int* __restrict__ order,
                                                      const unsigned short* __restrict__ W1t,
                                                      const float* __restrict__ b1,
                                                      const float* __restrict__ W2,
                                                      const float* __restrict__ b2,
                                                      float* __restrict__ out, int E) {
  __shared__ unsigned short Wt[64 * 200];
  __shared__ float s_coef[128];
  const int tid = threadIdx.x;
  if (tid < 64) {
    float mean = sums_e3[tid] / (float)E;
    float var = sums_e3[64 + tid] / (float)E - mean * mean;
    float sc = ge3[tid] * rsqrtf(var + 1e-5f);
    s_coef[tid] = sc;
    s_coef[64 + tid] = be3[tid] - mean * sc;
  }
  for (int i = tid; i < 1536; i += 256) {
    int n = i / 24, kc = (i % 24) * 8;
    *reinterpret_cast<uint4*>(&Wt[n * 200 + kc]) =
        *reinterpret_cast<const uint4*>(W1t + n * 192 + kc);
  }
  __syncthreads();
  const int wid = tid >> 6, lane = tid & 63;
  const int col = lane & 15, g = lane >> 4;
  float b1v[4], w2v[4];
#pragma unroll
  for (int nt = 0; nt < 4; ++nt) { b1v[nt] = b1[nt * 16 + col]; w2v[nt] = W2[nt * 16 + col]; }
  const float bb2 = b2[0];
  const int ntiles = (E + 15) / 16;
  const int stride = gridDim.x * 4;
  int tw = xcd_vb() * 4 + wid;
  int2 idx_n = make_int2(0, 0);
  uint4 eo_n0 = {}, eo_n1 = {}, hv_n0 = {}, hv_n1 = {};
  if (tw < ntiles) {
    int p = tw * 16 + col; if (p >= E) p = E - 1;
    idx_n = pedge[p];
    const unsigned short* ep = e + (size_t)p * 64 + g * 8;
    eo_n0 = *reinterpret_cast<const uint4*>(ep);
    eo_n1 = *reinterpret_cast<const uint4*>(ep + 32);
    const unsigned short* hp = ehat3 + (size_t)p * 64 + g * 8;
    hv_n0 = *reinterpret_cast<const uint4*>(hp);
    hv_n1 = *reinterpret_cast<const uint4*>(hp + 32);
  }
  for (; tw < ntiles; tw += stride) {
    const int eb = tw * 16;
    int p = eb + col;
    const bool valid = p < E;
    if (!valid) p = E - 1;
    const int se = idx_n.x, de = idx_n.y;
    const uint4 eoc[2] = {eo_n0, eo_n1};
    const uint4 hvc[2] = {hv_n0, hv_n1};
    short8 haf[4];
#pragma unroll
    for (int ks = 0; ks < 4; ++ks) {
      const unsigned short* hp = hb + (size_t)(ks < 2 ? se : de) * 64 + (ks & 1) * 32 + g * 8;
      haf[ks] = g_frag(hp);
    }
    const int twn = tw + stride;
    if (twn < ntiles) {
      int pn = twn * 16 + col; if (pn >= E) pn = E - 1;
      idx_n = pedge[pn];
      const unsigned short* ep = e + (size_t)pn * 64 + g * 8;
      eo_n0 = *reinterpret_cast<const uint4*>(ep);
      eo_n1 = *reinterpret_cast<const uint4*>(ep + 32);
      const unsigned short* hp = ehat3 + (size_t)pn * 64 + g * 8;
      hv_n0 = *reinterpret_cast<const uint4*>(hp);
      hv_n1 = *reinterpret_cast<const uint4*>(hp + 32);
    }
    f32x4 acc[4] = {};
#pragma unroll
    for (int ks = 0; ks < 6; ++ks) {
      short8 af;
      if (ks < 4) {
        af = haf[ks];
      } else {
        const int kse = ks - 4;
        const int c0 = kse * 32 + g * 8;
        const uint4 eo = eoc[kse];
        const uint4 hv = hvc[kse];
        float4 a0 = make_float4(bfl(eo.x), bfh(eo.x), bfl(eo.y), bfh(eo.y));
        float4 a1 = make_float4(bfl(eo.z), bfh(eo.z), bfl(eo.w), bfh(eo.w));
        float4 sc0 = *reinterpret_cast<const float4*>(&s_coef[c0]);
        float4 sc1 = *reinterpret_cast<const float4*>(&s_coef[c0 + 4]);
        float4 sh0 = *reinterpret_cast<const float4*>(&s_coef[64 + c0]);
        float4 sh1 = *reinterpret_cast<const float4*>(&s_coef[64 + c0 + 4]);
        a0.x += fmaxf(fmaf(sc0.x, bfl(hv.x), sh0.x), 0.f);
        a0.y += fmaxf(fmaf(sc0.y, bfh(hv.x), sh0.y), 0.f);
        a0.z += fmaxf(fmaf(sc0.z, bfl(hv.y), sh0.z), 0.f);
        a0.w += fmaxf(fmaf(sc0.w, bfh(hv.y), sh0.w), 0.f);
        a1.x += fmaxf(fmaf(sc1.x, bfl(hv.z), sh1.x), 0.f);
        a1.y += fmaxf(fmaf(sc1.y, bfh(hv.z), sh1.y), 0.f);
        a1.z += fmaxf(fmaf(sc1.z, bfl(hv.w), sh1.z), 0.f);
        a1.w += fmaxf(fmaf(sc1.w, bfh(hv.w), sh1.w), 0.f);
        af = pack_bf16x8(a0, a1);
      }
#pragma unroll
      for (int nt = 0; nt < 4; ++nt) {
        short8 bb = lds_frag(&Wt[(nt * 16 + col) * 200 + ks * 32 + g * 8]);
        acc[nt] = __builtin_amdgcn_mfma_f32_16x16x32_bf16(af, bb, acc[nt], 0, 0, 0);
      }
    }
    float pr[4];
#pragma unroll
    for (int r = 0; r < 4; ++r) {
      float s = 0.f;
#pragma unroll
      for (int nt = 0; nt < 4; ++nt)
        s = fmaf(fmaxf(acc[nt][r] + b1v[nt], 0.f), w2v[nt], s);
      pr[r] = s;
    }
#pragma unroll
    for (int off = 1; off <= 8; off <<= 1)
#pragma unroll
      for (int r = 0; r < 4; ++r)
        pr[r] += __shfl_xor(pr[r], off, 64);
    if (col == 0) {
#pragma unroll
      for (int r = 0; r < 4; ++r) {
        int m = eb + g * 4 + r;
        if (m < E) out[order[m]] = pr[r] + bb2;
      }
    }
  }
}

extern "C" void kernel_launch(void* const* d_in, const int* in_sizes, int n_in,
                              void* d_out, int out_size, void* d_ws, size_t ws_size,
                              hipStream_t stream) {
  const float* reads  = (const float*)d_in[0];
  const int*   src    = (const int*)d_in[1];
  const int*   dst    = (const int*)d_in[2];
  const float* sim    = (const float*)d_in[3];
  const float* olen   = (const float*)d_in[4];
  const float* conv_w = (const float*)d_in[5];
  const float* conv_b = (const float*)d_in[6];
  const float* We     = (const float*)d_in[7];
  const float* be     = (const float*)d_in[8];
  const float* A1     = (const float*)d_in[9];
  const float* A2     = (const float*)d_in[10];
  const float* A3     = (const float*)d_in[11];
  const float* bA1    = (const float*)d_in[12];
  const float* bA2    = (const float*)d_in[13];
  const float* bA3    = (const float*)d_in[14];
  const float* U      = (const float*)d_in[15];
  const float* V      = (const float*)d_in[16];
  const float* bU     = (const float*)d_in[17];
  const float* bV     = (const float*)d_in[18];
  const float* bnhg   = (const float*)d_in[19];
  const float* bnhb   = (const float*)d_in[20];
  const float* bneg   = (const float*)d_in[21];
  const float* bneb   = (const float*)d_in[22];
  const float* W1     = (const float*)d_in[23];
  const float* b1     = (const float*)d_in[24];
  const float* W2     = (const float*)d_in[25];
  const float* b2     = (const float*)d_in[26];

  const int N = in_sizes[0] / 512;
  const int E = in_sizes[1];

  float* fp = (float*)d_ws;
  float* hA   = fp; fp += (size_t)N * 64;
  float* hB   = fp; fp += (size_t)N * 64;
  float* hhat = fp; fp += (size_t)N * 64;
  float* XU   = fp; fp += (size_t)N * 64;
  float* sums = fp; fp += 1024;
  unsigned short* up = (unsigned short*)fp;
  unsigned short* e     = up; up += (size_t)E * 64;
  unsigned short* ehatA = up; up += (size_t)E * 64;
  unsigned short* ehatB = up; up += (size_t)E * 64;
  unsigned short* XA1 = up; up += (size_t)N * 64;
  unsigned short* XA2 = up; up += (size_t)N * 64;
  unsigned short* XV  = up; up += (size_t)N * 64;
  unsigned short* hb  = up; up += (size_t)N * 64;
  unsigned short* Wt  = up; up += 20 * 4096 + 12288;
  int* ip = (int*)up;
  int* order   = ip; ip += E;
  int* psrc    = ip; ip += E;
  int2* pedge  = (int2*)ip; ip += 2 * (size_t)E;
  int* cnt     = ip; ip += N;
  int* nxt     = ip; ip += N;
  int* row_ptr = ip; ip += N + 1;
  float* out = (float*)d_out;

  hipMemsetAsync(cnt, 0, sizeof(int) * N, stream);
  hipMemsetAsync(sums, 0, sizeof(float) * 1024, stream);
  k_hist<<<(E + 255) / 256, 256, 0, stream>>>(dst, cnt, E);
  k_prep<<<21, 256, 0, stream>>>(A1, A2, V, U, A3, W1, Wt);
  k_scan<<<1, 1024, 0, stream>>>(cnt, row_ptr, nxt, N, E);
  k_scatter<<<(E + 255) / 256, 256, 0, stream>>>(dst, src, nxt, order, psrc, pedge, E);

  const int ngroups = (N + 3) / 4;
  const int CG = ngroups < 1024 ? ngroups : 1024;  // 36 KB LDS -> 4 blocks/CU
  k_conv_mfma<<<CG, 256, 0, stream>>>(reads, conv_w, conv_b, hA, N);

  const int EPBLK = 1024;
  const int APBLK = 1024;
  const int NPB = 512;
  float* hin = hA;
  float* hout = hB;
  unsigned short* ehat_cur = ehatA;
  unsigned short* ehat_prev = ehatB;
  for (int l = 0; l < 4; ++l) {
    ehat_cur = (l & 1) ? ehatB : ehatA;
    ehat_prev = (l & 1) ? ehatA : ehatB;
    float* sums_e = sums + l * 128;
    float* sums_h = sums + 512 + l * 128;
    k_node_mfma<<<NPB, 256, 0, stream>>>(
        hin, (l > 0) ? hout : nullptr, hhat,
        (l > 0) ? (sums + 512 + (l - 1) * 128) : sums,
        bnhg + (l > 0 ? (l - 1) * 64 : 0), bnhb + (l > 0 ? (l - 1) * 64 : 0),
        Wt + l * 5 * 4096,
        bA1 + l * 64, bA2 + l * 64, bV + l * 64, bU + l * 64,
        XA1, XA2, XV, XU, N, l > 0 ? 1 : 0);
    if (l > 0) { float* t = hin; hin = hout; hout = t; }
    if (l == 0) {
      k_edge_mfma0<<<EPBLK, 256, 0, stream>>>(
          e, ehat_cur, sim, olen, order, We, be, pedge, XA1, XA2,
          Wt + 4 * 4096, bA3, sums_e, E);
    } else {
      k_edge_mfma<<<EPBLK, 256, 0, stream>>>(
          e, ehat_prev, ehat_cur, sums + (l - 1) * 128,
          bneg + (l - 1) * 64, bneb + (l - 1) * 64,
          pedge, XA1, XA2, Wt + (l * 5 + 4) * 4096, bA3 + l * 64, sums_e, E);
    }
    k_agg<<<APBLK, 256, 0, stream>>>(row_ptr, psrc, ehat_cur, XV, XU, hhat, sums_h, N);
  }

  k_update_h<<<(N * 16 + 255) / 256, 256, 0, stream>>>(
      hin, hb, hhat, sums + 512 + 3 * 128, bnhg + 3 * 64, bnhb + 3 * 64, N);
  k_decoder_mfma<<<EPBLK, 256, 0, stream>>>(
      hb, e, ehat_cur, sums + 3 * 128, bneg + 3 * 64, bneb + 3 * 64,
      pedge, order, Wt + 20 * 4096, b1, W2, b2, out, E);
}